// Round 2
// baseline (39286.267 us; speedup 1.0000x reference)
//
#include <hip/hip_runtime.h>
#include <hip/hip_bf16.h>
#include <math.h>

#define D_MODEL 1024
#define D_INNER 2048
#define D_STATE 16
#define D_CONV 4
#define DT_RANK 64
#define N_LAYER 8
#define INPUT_DIM 256
#define BATCH 16
#define TT 64
#define S_IN 13
#define SEQ_S 16                 // S_IN + 3
#define L_SEQ 1024               // TT * SEQ_S
#define XZ_LD (2 * D_INNER)      // 4096
#define PROJ_N 96                // DT_RANK + 2*D_STATE
#define EPS 1e-5f

// ---------------------------------------------------------------------------
// Generic fp32 GEMM: C[M,N] = A[M,K] @ W[N,K]^T (+bias) (+activation)
// act: 0 = none, 1 = softplus. 64x64 tile, 256 thr, 4x4 microtile, BK=16.
// ---------------------------------------------------------------------------
#define BM 64
#define BN 64
#define BK 16

__global__ __launch_bounds__(256) void gemm_bt(
    const float* __restrict__ A, int lda,
    const float* __restrict__ W,
    const float* __restrict__ bias,
    float* __restrict__ C, int ldc,
    int M, int N, int K, int act)
{
  __shared__ float As[BK][BM + 4];
  __shared__ float Bs[BK][BN + 4];
  const int tid = threadIdx.x;
  const int tx = tid & 15;   // n direction
  const int ty = tid >> 4;   // m direction
  const int m0 = blockIdx.x * BM;
  const int n0 = blockIdx.y * BN;
  const int kk = tid & 15;
  const int rr = tid >> 4;

  float acc[4][4] = {};

  for (int k0 = 0; k0 < K; k0 += BK) {
#pragma unroll
    for (int i = 0; i < 4; ++i) {
      int m = rr + i * 16;
      float v = 0.f;
      if (m0 + m < M) v = A[(size_t)(m0 + m) * lda + (k0 + kk)];
      As[kk][m] = v;
    }
#pragma unroll
    for (int i = 0; i < 4; ++i) {
      int n = rr + i * 16;
      float v = 0.f;
      if (n0 + n < N) v = W[(size_t)(n0 + n) * K + (k0 + kk)];
      Bs[kk][n] = v;
    }
    __syncthreads();
#pragma unroll
    for (int k = 0; k < BK; ++k) {
      float4 a4 = *(const float4*)&As[k][ty * 4];
      float4 b4 = *(const float4*)&Bs[k][tx * 4];
      float av[4] = {a4.x, a4.y, a4.z, a4.w};
      float bv[4] = {b4.x, b4.y, b4.z, b4.w};
#pragma unroll
      for (int i = 0; i < 4; ++i)
#pragma unroll
        for (int j = 0; j < 4; ++j)
          acc[i][j] = fmaf(av[i], bv[j], acc[i][j]);
    }
    __syncthreads();
  }

#pragma unroll
  for (int i = 0; i < 4; ++i) {
    int m = m0 + ty * 4 + i;
    if (m >= M) continue;
#pragma unroll
    for (int j = 0; j < 4; ++j) {
      int n = n0 + tx * 4 + j;
      if (n >= N) continue;
      float v = acc[i][j];
      if (bias) v += bias[n];
      if (act == 1) v = (v > 20.f) ? v : log1pf(__expf(v));  // softplus
      C[(size_t)m * ldc + n] = v;
    }
  }
}

// ---------------------------------------------------------------------------
__device__ __forceinline__ float block_reduce_sum_256(float v)
{
  __shared__ float red[4];
#pragma unroll
  for (int off = 32; off > 0; off >>= 1) v += __shfl_xor(v, off, 64);
  const int tid = threadIdx.x;
  if ((tid & 63) == 0) red[tid >> 6] = v;
  __syncthreads();
  return red[0] + red[1] + red[2] + red[3];
}

// ---------------------------------------------------------------------------
// Token assembly for one chunk: hs = concat([cls, h, 0, 0]) + pe ; res = 0
// grid = bc*1024 blocks (one per local row), 256 threads x float4.
// ---------------------------------------------------------------------------
__global__ __launch_bounds__(256) void seq_build(
    const float* __restrict__ hflat, const float* __restrict__ cls,
    float* __restrict__ hs, float* __restrict__ res)
{
  const int row = blockIdx.x;            // b_local*1024 + l
  const int bl = row >> 10;
  const int l = row & (L_SEQ - 1);
  const int t = l >> 4;                  // frame (0..63)
  const int s = l & 15;                  // token within frame
  const int tid = threadIdx.x;

  float4 v;
  if (s == 0) {
    v = ((const float4*)cls)[tid];
  } else if (s <= S_IN) {
    const size_t hrow = ((size_t)(bl * TT + t) * S_IN + (s - 1)) * D_MODEL;
    v = ((const float4*)(hflat + hrow))[tid];
  } else {
    v = make_float4(0.f, 0.f, 0.f, 0.f);
  }

  const float cexp = -logf(10000.f) / (float)D_MODEL;
  float pe[4];
#pragma unroll
  for (int j = 0; j < 4; ++j) {
    int d = tid * 4 + j;
    int i2 = d & ~1;
    float ang = (float)t * expf((float)i2 * cexp);
    pe[j] = (d & 1) ? cosf(ang) : sinf(ang);
  }
  v.x += pe[0]; v.y += pe[1]; v.z += pe[2]; v.w += pe[3];

  const size_t base = (size_t)row * D_MODEL;
  ((float4*)(hs + base))[tid] = v;
  ((float4*)(res + base))[tid] = make_float4(0.f, 0.f, 0.f, 0.f);
}

// ---------------------------------------------------------------------------
// res += hs ; hn = rmsnorm(res) * w.  SAFE for hs==hn (read-before-write
// per-thread, same addresses).
// ---------------------------------------------------------------------------
__global__ __launch_bounds__(256) void add_rmsnorm(
    float* __restrict__ res, const float* hs,
    float* hn, const float* __restrict__ w)
{
  const int row = blockIdx.x;
  const int tid = threadIdx.x;
  const size_t base = (size_t)row * D_MODEL;
  float4 r = ((const float4*)(res + base))[tid];
  float4 h = ((const float4*)(hs + base))[tid];
  r.x += h.x; r.y += h.y; r.z += h.z; r.w += h.w;
  ((float4*)(res + base))[tid] = r;
  float ss = r.x * r.x + r.y * r.y + r.z * r.z + r.w * r.w;
  ss = block_reduce_sum_256(ss);
  const float scale = rsqrtf(ss * (1.f / (float)D_MODEL) + EPS);
  float4 wv = ((const float4*)w)[tid];
  float4 o = make_float4(r.x * scale * wv.x, r.y * scale * wv.y,
                         r.z * scale * wv.z, r.w * scale * wv.w);
  ((float4*)(hn + base))[tid] = o;
}

// ---------------------------------------------------------------------------
// Depthwise causal conv (K=4) + silu over the flattened length L_SEQ per b.
// ---------------------------------------------------------------------------
__global__ __launch_bounds__(256) void conv_silu(
    const float* __restrict__ xz, const float* __restrict__ cw,
    const float* __restrict__ cb, float* __restrict__ xc)
{
  const int c = blockIdx.x * 256 + threadIdx.x;
  const int t = blockIdx.y;
  const int bl = blockIdx.z;
  const size_t row = (size_t)bl * L_SEQ + t;

  const float w0 = cw[c * D_CONV + 0];
  const float w1 = cw[c * D_CONV + 1];
  const float w2 = cw[c * D_CONV + 2];
  const float w3 = cw[c * D_CONV + 3];

  float acc = cb[c];
  if (t >= 3) acc = fmaf(w0, xz[(row - 3) * XZ_LD + c], acc);
  if (t >= 2) acc = fmaf(w1, xz[(row - 2) * XZ_LD + c], acc);
  if (t >= 1) acc = fmaf(w2, xz[(row - 1) * XZ_LD + c], acc);
  acc = fmaf(w3, xz[row * XZ_LD + c], acc);

  acc = acc / (1.f + __expf(-acc));      // silu
  xc[row * D_INNER + c] = acc;
}

// ---------------------------------------------------------------------------
// Selective scan: thread per (b_local, channel); 16 states in registers.
// dt in xz[..., :2048] (dt_proj wrote with ldc=XZ_LD), z in xz[..., 2048:].
// y (+D-skip, *silu(z)) overwrites xc in place.
// ---------------------------------------------------------------------------
__global__ __launch_bounds__(256) void scan_kernel(
    const float* __restrict__ xz, float* xc, const float* __restrict__ proj,
    const float* __restrict__ Alog, const float* __restrict__ Dp)
{
  const int dim = blockIdx.x * 256 + threadIdx.x;  // 0..2047
  const int bl = blockIdx.y;

  float A[D_STATE], h[D_STATE];
#pragma unroll
  for (int s = 0; s < D_STATE; ++s) {
    A[s] = -__expf(Alog[(size_t)dim * D_STATE + s]);
    h[s] = 0.f;
  }
  const float Dv = Dp[dim];

  for (int t = 0; t < L_SEQ; ++t) {
    const size_t r = (size_t)bl * L_SEQ + t;
    const float dtv = xz[r * XZ_LD + dim];
    const float zv  = xz[r * XZ_LD + D_INNER + dim];
    const float u   = xc[r * D_INNER + dim];
    const float* bc = proj + r * PROJ_N;           // wave-uniform
    const float du = dtv * u;
    float yv = 0.f;
#pragma unroll
    for (int s = 0; s < D_STATE; ++s) {
      float dA = __expf(dtv * A[s]);
      h[s] = fmaf(dA, h[s], du * bc[DT_RANK + s]);           // B
      yv = fmaf(h[s], bc[DT_RANK + D_STATE + s], yv);        // C
    }
    yv = fmaf(Dv, u, yv);
    const float g = zv / (1.f + __expf(-zv));      // silu(z)
    xc[r * D_INNER + dim] = yv * g;
  }
}

// ---------------------------------------------------------------------------
// Final pooled rmsnorm on cls rows of this chunk. grid = bc*64 blocks.
// ---------------------------------------------------------------------------
__global__ __launch_bounds__(256) void pool_norm(
    const float* __restrict__ hs, const float* __restrict__ res,
    const float* __restrict__ w, float* __restrict__ out, int b0)
{
  const int idx = blockIdx.x;                      // b_local*64 + t
  const int bl = idx >> 6;
  const int t = idx & 63;
  const size_t base = ((size_t)bl * L_SEQ + (size_t)t * SEQ_S) * D_MODEL;
  const int tid = threadIdx.x;
  float4 h = ((const float4*)(hs + base))[tid];
  float4 r = ((const float4*)(res + base))[tid];
  float4 v = make_float4(h.x + r.x, h.y + r.y, h.z + r.z, h.w + r.w);
  float ss = v.x * v.x + v.y * v.y + v.z * v.z + v.w * v.w;
  ss = block_reduce_sum_256(ss);
  const float scale = rsqrtf(ss * (1.f / (float)D_MODEL) + EPS);
  float4 wv = ((const float4*)w)[tid];
  float4 o = make_float4(v.x * scale * wv.x, v.y * scale * wv.y,
                         v.z * scale * wv.z, v.w * scale * wv.w);
  const size_t orow = (size_t)((b0 + bl) * TT + t) * D_MODEL;
  ((float4*)(out + orow))[tid] = o;
}

// ---------------------------------------------------------------------------
extern "C" void kernel_launch(void* const* d_in, const int* in_sizes, int n_in,
                              void* d_out, int out_size, void* d_ws, size_t ws_size,
                              hipStream_t stream)
{
  const float* x      = (const float*)d_in[0];
  // d_in[1] = tt (int scalar, == 64): compiled in as TT
  const float* w_in   = (const float*)d_in[2];
  const float* b_in   = (const float*)d_in[3];
  const float* cls    = (const float*)d_in[4];
  const float* norm_w = (const float*)d_in[5];
  const float* ipw    = (const float*)d_in[6];
  const float* cw     = (const float*)d_in[7];
  const float* cb     = (const float*)d_in[8];
  const float* xpw    = (const float*)d_in[9];
  const float* dtw    = (const float*)d_in[10];
  const float* dtb    = (const float*)d_in[11];
  const float* Alog   = (const float*)d_in[12];
  const float* Dp     = (const float*)d_in[13];
  const float* opw    = (const float*)d_in[14];
  const float* normfw = (const float*)d_in[15];
  float* out = (float*)d_out;

  // Per-batch footprint (floats): res 1024 + hs/hn 1024 + xz 4096 + xc 2048
  // + proj 96, all x L_SEQ rows.
  const size_t perB = (size_t)L_SEQ * (D_MODEL + D_MODEL + XZ_LD + D_INNER + PROJ_N);
  int bc = 0;
  for (int c = 16; c >= 1; c >>= 1)
    if (perB * (size_t)c * sizeof(float) <= ws_size) { bc = c; break; }
  if (bc == 0) return;  // < 34 MB of scratch: cannot run

  const int R = bc * L_SEQ;            // rows per chunk
  float* ws   = (float*)d_ws;
  float* res  = ws;
  float* hsn  = res + (size_t)R * D_MODEL;    // hs and hn share (see add_rmsnorm)
  float* xz   = hsn + (size_t)R * D_MODEL;
  float* xc   = xz + (size_t)R * XZ_LD;
  float* proj = xc + (size_t)R * D_INNER;

  for (int b0 = 0; b0 < BATCH; b0 += bc) {
    // 1. input projection for this chunk: hflat = x_chunk @ w_in^T + b_in
    //    staged inside the (currently unused) xz region.
    const int Mx = bc * TT * S_IN;             // rows of x in chunk
    float* hflat = xz;
    gemm_bt<<<dim3(Mx / BM, D_MODEL / BN), 256, 0, stream>>>(
        x + (size_t)b0 * TT * S_IN * INPUT_DIM, INPUT_DIM,
        w_in, b_in, hflat, D_MODEL, Mx, D_MODEL, INPUT_DIM, 0);

    // 2. token assembly + positional encoding: hsn = seq, res = 0
    seq_build<<<R, 256, 0, stream>>>(hflat, cls, hsn, res);

    for (int l = 0; l < N_LAYER; ++l) {
      // res += hs ; hn = rmsnorm(res) * norm_w[l]   (hs==hn buffer)
      add_rmsnorm<<<R, 256, 0, stream>>>(res, hsn, hsn,
          norm_w + (size_t)l * D_MODEL);

      // xz = hn @ ipw[l]^T     (R x 4096, K=1024)
      gemm_bt<<<dim3(R / BM, XZ_LD / BN), 256, 0, stream>>>(
          hsn, D_MODEL, ipw + (size_t)l * XZ_LD * D_MODEL, nullptr,
          xz, XZ_LD, R, XZ_LD, D_MODEL, 0);

      // xc = silu(conv(xm))
      conv_silu<<<dim3(D_INNER / 256, L_SEQ, bc), 256, 0, stream>>>(
          xz, cw + (size_t)l * D_INNER * D_CONV, cb + (size_t)l * D_INNER, xc);

      // proj = xc @ xpw[l]^T   (R x 96, K=2048)
      gemm_bt<<<dim3(R / BM, 2), 256, 0, stream>>>(
          xc, D_INNER, xpw + (size_t)l * PROJ_N * D_INNER, nullptr,
          proj, PROJ_N, R, PROJ_N, D_INNER, 0);

      // dt = softplus(proj[:, :64] @ dtw[l]^T + dtb[l]) -> dead xm half of xz
      gemm_bt<<<dim3(R / BM, D_INNER / BN), 256, 0, stream>>>(
          proj, PROJ_N, dtw + (size_t)l * D_INNER * DT_RANK,
          dtb + (size_t)l * D_INNER, xz, XZ_LD,
          R, D_INNER, DT_RANK, 1);

      // selective scan + D-skip + silu(z) gate; overwrites xc in place
      scan_kernel<<<dim3(D_INNER / 256, bc), 256, 0, stream>>>(
          xz, xc, proj, Alog + (size_t)l * D_INNER * D_STATE,
          Dp + (size_t)l * D_INNER);

      // hs = y @ opw[l]^T      (R x 1024, K=2048)
      gemm_bt<<<dim3(R / BM, D_MODEL / BN), 256, 0, stream>>>(
          xc, D_INNER, opw + (size_t)l * D_MODEL * D_INNER, nullptr,
          hsn, D_MODEL, R, D_MODEL, D_INNER, 0);
    }

    // final pooled rmsnorm for this chunk's cls rows
    pool_norm<<<bc * TT, 256, 0, stream>>>(hsn, res, normfw, out, b0);
  }
}

// Round 3
// 21729.158 us; speedup vs baseline: 1.8080x; 1.8080x over previous
//
#include <hip/hip_runtime.h>
#include <hip/hip_bf16.h>
#include <math.h>

#define D_MODEL 1024
#define D_INNER 2048
#define D_STATE 16
#define D_CONV 4
#define DT_RANK 64
#define N_LAYER 8
#define INPUT_DIM 256
#define BATCH 16
#define TT 64
#define S_IN 13
#define SEQ_S 16                 // S_IN + 3
#define L_SEQ 1024               // TT * SEQ_S
#define XZ_LD (2 * D_INNER)      // 4096
#define PROJ_N 96                // DT_RANK + 2*D_STATE
#define EPS 1e-5f

typedef __attribute__((ext_vector_type(8))) short short8;   // 8 x bf16 (4 VGPRs)
typedef __attribute__((ext_vector_type(4))) float f32x4;    // MFMA acc

// fp32 -> bf16 bits, round-to-nearest-even
__device__ __forceinline__ unsigned short f2bu(float x) {
  unsigned int u = __float_as_uint(x);
  unsigned int r = (u + 0x7fffu + ((u >> 16) & 1u)) >> 16;
  return (unsigned short)r;
}

__device__ __forceinline__ void gload_lds16(const void* g, void* l) {
  __builtin_amdgcn_global_load_lds(
      (const __attribute__((address_space(1))) void*)g,
      (__attribute__((address_space(3))) void*)l, 16, 0, 0);
}

// ---------------------------------------------------------------------------
// bf16 MFMA GEMM: C[M,N] = A[M,K](bf16) @ W[N,K](bf16)^T (+bias)(+act)
// 128x128 block tile, BK=32, 4 waves each computing 64x64 via 4x4 of
// 16x16x32 MFMA. global_load_lds width-16 staging (m97 structure).
// Row clamping handles M,N not multiple of 128; K must be multiple of 32.
// act: 0 none, 1 softplus. Cb (optional) = bf16 copy of C.
// ---------------------------------------------------------------------------
__global__ __launch_bounds__(256) void gemm_mfma(
    const unsigned short* __restrict__ A, int lda,
    const unsigned short* __restrict__ W, int ldw,
    const float* __restrict__ bias,
    float* __restrict__ C, int ldc,
    unsigned short* __restrict__ Cb, int ldcb,
    int M, int N, int K, int act)
{
  __shared__ unsigned short As[128 * 32];  // 8 KB, row-major [128][32]
  __shared__ unsigned short Ws[128 * 32];  // 8 KB
  const int tid  = threadIdx.x;
  const int wave = tid >> 6;
  const int lane = tid & 63;
  const int m0 = blockIdx.x * 128;
  const int n0 = blockIdx.y * 128;
  const int wm = (wave & 1) * 64;          // wave quadrant in C
  const int wn = (wave >> 1) * 64;

  // staging geometry: each wave stages 32 rows (2 issues x 16 rows),
  // lane covers row (lane>>2), 16B col chunk (lane&3)
  const int srow = (lane >> 2);
  const int scol = (lane & 3) * 8;         // bf16 elements

  f32x4 acc[4][4] = {};

  for (int k0 = 0; k0 < K; k0 += 32) {
#pragma unroll
    for (int i = 0; i < 2; ++i) {
      int rowA = m0 + wave * 32 + i * 16 + srow;
      if (rowA > M - 1) rowA = M - 1;
      gload_lds16(A + (size_t)rowA * lda + k0 + scol,
                  &As[(wave * 32 + i * 16) * 32]);
      int rowW = n0 + wave * 32 + i * 16 + srow;
      if (rowW > N - 1) rowW = N - 1;
      gload_lds16(W + (size_t)rowW * ldw + k0 + scol,
                  &Ws[(wave * 32 + i * 16) * 32]);
    }
    __syncthreads();   // compiler emits vmcnt(0) drain before s_barrier

    short8 af[4], bf[4];
#pragma unroll
    for (int mi = 0; mi < 4; ++mi)
      af[mi] = *(const short8*)&As[(wm + mi * 16 + (lane & 15)) * 32 + (lane >> 4) * 8];
#pragma unroll
    for (int ni = 0; ni < 4; ++ni)
      bf[ni] = *(const short8*)&Ws[(wn + ni * 16 + (lane & 15)) * 32 + (lane >> 4) * 8];
#pragma unroll
    for (int mi = 0; mi < 4; ++mi)
#pragma unroll
      for (int ni = 0; ni < 4; ++ni)
        acc[mi][ni] = __builtin_amdgcn_mfma_f32_16x16x32_bf16(
            af[mi], bf[ni], acc[mi][ni], 0, 0, 0);
    __syncthreads();
  }

  // epilogue: C/D layout col=lane&15, row=(lane>>4)*4+r   [m89-verified]
#pragma unroll
  for (int mi = 0; mi < 4; ++mi) {
#pragma unroll
    for (int ni = 0; ni < 4; ++ni) {
      const int col = n0 + wn + ni * 16 + (lane & 15);
      if (col >= N) continue;
#pragma unroll
      for (int r = 0; r < 4; ++r) {
        const int row = m0 + wm + mi * 16 + (lane >> 4) * 4 + r;
        if (row >= M) continue;
        float v = acc[mi][ni][r];
        if (bias) v += bias[col];
        if (act == 1) v = (v > 20.f) ? v : log1pf(__expf(v));  // softplus
        C[(size_t)row * ldc + col] = v;
        if (Cb) Cb[(size_t)row * ldcb + col] = f2bu(v);
      }
    }
  }
}

// ---------------------------------------------------------------------------
// generic fp32 -> bf16 conversion (float4 vectorized), n must be mult of 4
// ---------------------------------------------------------------------------
__global__ __launch_bounds__(256) void cvt_bf16(
    const float* __restrict__ in, unsigned short* __restrict__ out, int n4)
{
  int i = blockIdx.x * 256 + threadIdx.x;
  if (i < n4) {
    float4 v = ((const float4*)in)[i];
    ushort4 o;
    o.x = f2bu(v.x); o.y = f2bu(v.y); o.z = f2bu(v.z); o.w = f2bu(v.w);
    ((ushort4*)out)[i] = o;
  }
}

// ---------------------------------------------------------------------------
__device__ __forceinline__ float block_reduce_sum_256(float v)
{
  __shared__ float red[4];
#pragma unroll
  for (int off = 32; off > 0; off >>= 1) v += __shfl_xor(v, off, 64);
  const int tid = threadIdx.x;
  if ((tid & 63) == 0) red[tid >> 6] = v;
  __syncthreads();
  return red[0] + red[1] + red[2] + red[3];
}

// ---------------------------------------------------------------------------
// Token assembly: hs = concat([cls, h, 0, 0]) + pe ; res = 0
// ---------------------------------------------------------------------------
__global__ __launch_bounds__(256) void seq_build(
    const float* __restrict__ hflat, const float* __restrict__ cls,
    float* __restrict__ hs, float* __restrict__ res)
{
  const int row = blockIdx.x;            // b_local*1024 + l
  const int bl = row >> 10;
  const int l = row & (L_SEQ - 1);
  const int t = l >> 4;
  const int s = l & 15;
  const int tid = threadIdx.x;

  float4 v;
  if (s == 0) {
    v = ((const float4*)cls)[tid];
  } else if (s <= S_IN) {
    const size_t hrow = ((size_t)(bl * TT + t) * S_IN + (s - 1)) * D_MODEL;
    v = ((const float4*)(hflat + hrow))[tid];
  } else {
    v = make_float4(0.f, 0.f, 0.f, 0.f);
  }

  const float cexp = -logf(10000.f) / (float)D_MODEL;
  float pe[4];
#pragma unroll
  for (int j = 0; j < 4; ++j) {
    int d = tid * 4 + j;
    int i2 = d & ~1;
    float ang = (float)t * expf((float)i2 * cexp);
    pe[j] = (d & 1) ? cosf(ang) : sinf(ang);
  }
  v.x += pe[0]; v.y += pe[1]; v.z += pe[2]; v.w += pe[3];

  const size_t base = (size_t)row * D_MODEL;
  ((float4*)(hs + base))[tid] = v;
  ((float4*)(res + base))[tid] = make_float4(0.f, 0.f, 0.f, 0.f);
}

// ---------------------------------------------------------------------------
// res += hs ; hn(bf16) = rmsnorm(res) * w
// ---------------------------------------------------------------------------
__global__ __launch_bounds__(256) void add_rmsnorm(
    float* __restrict__ res, const float* __restrict__ hs,
    unsigned short* __restrict__ hnb, const float* __restrict__ w)
{
  const int row = blockIdx.x;
  const int tid = threadIdx.x;
  const size_t base = (size_t)row * D_MODEL;
  float4 r = ((const float4*)(res + base))[tid];
  float4 h = ((const float4*)(hs + base))[tid];
  r.x += h.x; r.y += h.y; r.z += h.z; r.w += h.w;
  ((float4*)(res + base))[tid] = r;
  float ss = r.x * r.x + r.y * r.y + r.z * r.z + r.w * r.w;
  ss = block_reduce_sum_256(ss);
  const float scale = rsqrtf(ss * (1.f / (float)D_MODEL) + EPS);
  float4 wv = ((const float4*)w)[tid];
  ushort4 o;
  o.x = f2bu(r.x * scale * wv.x);
  o.y = f2bu(r.y * scale * wv.y);
  o.z = f2bu(r.z * scale * wv.z);
  o.w = f2bu(r.w * scale * wv.w);
  ((ushort4*)(hnb + base))[tid] = o;
}

// ---------------------------------------------------------------------------
// Depthwise causal conv (K=4) + silu; writes xc fp32 (scan input) and
// xcb bf16 (x_proj GEMM input)
// ---------------------------------------------------------------------------
__global__ __launch_bounds__(256) void conv_silu(
    const float* __restrict__ xz, const float* __restrict__ cw,
    const float* __restrict__ cb, float* __restrict__ xc,
    unsigned short* __restrict__ xcb)
{
  const int c = blockIdx.x * 256 + threadIdx.x;
  const int t = blockIdx.y;
  const int bl = blockIdx.z;
  const size_t row = (size_t)bl * L_SEQ + t;

  const float w0 = cw[c * D_CONV + 0];
  const float w1 = cw[c * D_CONV + 1];
  const float w2 = cw[c * D_CONV + 2];
  const float w3 = cw[c * D_CONV + 3];

  float acc = cb[c];
  if (t >= 3) acc = fmaf(w0, xz[(row - 3) * XZ_LD + c], acc);
  if (t >= 2) acc = fmaf(w1, xz[(row - 2) * XZ_LD + c], acc);
  if (t >= 1) acc = fmaf(w2, xz[(row - 1) * XZ_LD + c], acc);
  acc = fmaf(w3, xz[row * XZ_LD + c], acc);

  acc = acc / (1.f + __expf(-acc));      // silu
  xc[row * D_INNER + c] = acc;
  xcb[row * D_INNER + c] = f2bu(acc);
}

// ---------------------------------------------------------------------------
// Selective scan v2: thread per (b, ch, state). 16 lanes per channel,
// butterfly shfl_xor reduce for y = C . h. 8x the occupancy of v1.
// dt in xz[...,:2048], z in xz[...,2048:], u = xc fp32.
// Output y*silu(z) written as bf16 into yb (= out_proj A operand).
// ---------------------------------------------------------------------------
__global__ __launch_bounds__(256) void scan2(
    const float* __restrict__ xz, const float* __restrict__ xc,
    const float* __restrict__ proj,
    const float* __restrict__ Alog, const float* __restrict__ Dp,
    unsigned short* __restrict__ yb)
{
  const int tid = threadIdx.x;
  const int s  = tid & 15;               // state
  const int cl = tid >> 4;               // local channel (16 per block)
  const int ch = blockIdx.x * 16 + cl;
  const int bl = blockIdx.y;

  const float As = -__expf(Alog[(size_t)ch * D_STATE + s]);
  const float Dv = Dp[ch];
  float h = 0.f;
  const size_t base = (size_t)bl * L_SEQ;

  for (int t = 0; t < L_SEQ; ++t) {
    const size_t r = base + t;
    const float dtv = xz[r * XZ_LD + ch];
    const float zv  = xz[r * XZ_LD + D_INNER + ch];
    const float u   = xc[r * D_INNER + ch];
    const float Bv  = proj[r * PROJ_N + DT_RANK + s];
    const float Cv  = proj[r * PROJ_N + DT_RANK + D_STATE + s];
    const float dA = __expf(dtv * As);
    h = fmaf(dA, h, dtv * u * Bv);
    float p = h * Cv;
    p += __shfl_xor(p, 1, 64);
    p += __shfl_xor(p, 2, 64);
    p += __shfl_xor(p, 4, 64);
    p += __shfl_xor(p, 8, 64);
    if (s == 0) {
      const float yv = fmaf(Dv, u, p);
      const float g = zv / (1.f + __expf(-zv));   // silu(z)
      yb[r * D_INNER + ch] = f2bu(yv * g);
    }
  }
}

// ---------------------------------------------------------------------------
// Final pooled rmsnorm on cls rows
// ---------------------------------------------------------------------------
__global__ __launch_bounds__(256) void pool_norm(
    const float* __restrict__ hs, const float* __restrict__ res,
    const float* __restrict__ w, float* __restrict__ out, int b0)
{
  const int idx = blockIdx.x;                      // b_local*64 + t
  const int bl = idx >> 6;
  const int t = idx & 63;
  const size_t base = ((size_t)bl * L_SEQ + (size_t)t * SEQ_S) * D_MODEL;
  const int tid = threadIdx.x;
  float4 h = ((const float4*)(hs + base))[tid];
  float4 r = ((const float4*)(res + base))[tid];
  float4 v = make_float4(h.x + r.x, h.y + r.y, h.z + r.z, h.w + r.w);
  float ss = v.x * v.x + v.y * v.y + v.z * v.z + v.w * v.w;
  ss = block_reduce_sum_256(ss);
  const float scale = rsqrtf(ss * (1.f / (float)D_MODEL) + EPS);
  float4 wv = ((const float4*)w)[tid];
  float4 o = make_float4(v.x * scale * wv.x, v.y * scale * wv.y,
                         v.z * scale * wv.z, v.w * scale * wv.w);
  const size_t orow = (size_t)((b0 + bl) * TT + t) * D_MODEL;
  ((float4*)(out + orow))[tid] = o;
}

// ---------------------------------------------------------------------------
extern "C" void kernel_launch(void* const* d_in, const int* in_sizes, int n_in,
                              void* d_out, int out_size, void* d_ws, size_t ws_size,
                              hipStream_t stream)
{
  const float* x      = (const float*)d_in[0];
  // d_in[1] = tt (int scalar, == 64): compiled in as TT
  const float* w_in   = (const float*)d_in[2];
  const float* b_in   = (const float*)d_in[3];
  const float* cls    = (const float*)d_in[4];
  const float* norm_w = (const float*)d_in[5];
  const float* ipw    = (const float*)d_in[6];
  const float* cw     = (const float*)d_in[7];
  const float* cb     = (const float*)d_in[8];
  const float* xpw    = (const float*)d_in[9];
  const float* dtw    = (const float*)d_in[10];
  const float* dtb    = (const float*)d_in[11];
  const float* Alog   = (const float*)d_in[12];
  const float* Dp     = (const float*)d_in[13];
  const float* opw    = (const float*)d_in[14];
  const float* normfw = (const float*)d_in[15];
  float* out = (float*)d_out;

  // ---- bf16 weight/x region (elements) ----
  const size_t N_WIN = (size_t)D_MODEL * INPUT_DIM;            //   262144
  const size_t N_IPW = (size_t)N_LAYER * XZ_LD * D_MODEL;      // 33554432
  const size_t N_XPW = (size_t)N_LAYER * PROJ_N * D_INNER;     //  1572864
  const size_t N_DTW = (size_t)N_LAYER * D_INNER * DT_RANK;    //  1048576
  const size_t N_OPW = (size_t)N_LAYER * D_MODEL * D_INNER;    // 16777216
  const size_t N_XB  = (size_t)BATCH * TT * S_IN * INPUT_DIM;  //  3407872
  const size_t N_BF  = N_WIN + N_IPW + N_XPW + N_DTW + N_OPW + N_XB;

  // per-batch activation bytes:
  // f32: res 1024 + hs 1024 + xz 4096 + xc 2048 + proj 96  = 8288 * 4
  // b16: hn 1024 + xcy 2048 + projb 96                     = 3168 * 2
  const size_t perB = (size_t)L_SEQ * (8288 * 4 + 3168 * 2);
  int bc = 0;
  for (int c = 16; c >= 1; c >>= 1)
    if (N_BF * 2 + perB * (size_t)c <= ws_size) { bc = c; break; }
  if (bc == 0) return;

  const int R = bc * L_SEQ;

  unsigned short* wb = (unsigned short*)d_ws;
  unsigned short* w_in_b = wb;
  unsigned short* ipw_b  = w_in_b + N_WIN;
  unsigned short* xpw_b  = ipw_b + N_IPW;
  unsigned short* dtw_b  = xpw_b + N_XPW;
  unsigned short* opw_b  = dtw_b + N_DTW;
  unsigned short* x_b    = opw_b + N_OPW;
  float* fw   = (float*)(x_b + N_XB);
  float* res  = fw;
  float* hs   = res + (size_t)R * D_MODEL;
  float* xz   = hs + (size_t)R * D_MODEL;
  float* xc   = xz + (size_t)R * XZ_LD;
  float* proj = xc + (size_t)R * D_INNER;
  unsigned short* hnb   = (unsigned short*)(proj + (size_t)R * PROJ_N);
  unsigned short* xcb   = hnb + (size_t)R * D_MODEL;   // xc bf16, then y bf16
  unsigned short* projb = xcb + (size_t)R * D_INNER;

  // ---- weight + x conversion (once per launch; ws re-poisoned each call) ----
  cvt_bf16<<<(int)((N_WIN/4 + 255)/256), 256, 0, stream>>>(w_in, w_in_b, (int)(N_WIN/4));
  cvt_bf16<<<(int)((N_IPW/4 + 255)/256), 256, 0, stream>>>(ipw, ipw_b, (int)(N_IPW/4));
  cvt_bf16<<<(int)((N_XPW/4 + 255)/256), 256, 0, stream>>>(xpw, xpw_b, (int)(N_XPW/4));
  cvt_bf16<<<(int)((N_DTW/4 + 255)/256), 256, 0, stream>>>(dtw, dtw_b, (int)(N_DTW/4));
  cvt_bf16<<<(int)((N_OPW/4 + 255)/256), 256, 0, stream>>>(opw, opw_b, (int)(N_OPW/4));
  cvt_bf16<<<(int)((N_XB/4  + 255)/256), 256, 0, stream>>>(x,   x_b,   (int)(N_XB/4));

  for (int b0 = 0; b0 < BATCH; b0 += bc) {
    // 1. input projection: hflat(=xz region) = x_chunk @ w_in^T + b_in
    const int Mx = bc * TT * S_IN;
    float* hflat = xz;
    gemm_mfma<<<dim3((Mx + 127) / 128, D_MODEL / 128), 256, 0, stream>>>(
        x_b + (size_t)b0 * TT * S_IN * INPUT_DIM, INPUT_DIM,
        w_in_b, INPUT_DIM, b_in, hflat, D_MODEL, nullptr, 0,
        Mx, D_MODEL, INPUT_DIM, 0);

    // 2. token assembly + positional encoding
    seq_build<<<R, 256, 0, stream>>>(hflat, cls, hs, res);

    for (int l = 0; l < N_LAYER; ++l) {
      add_rmsnorm<<<R, 256, 0, stream>>>(res, hs, hnb,
          norm_w + (size_t)l * D_MODEL);

      // xz = hn @ ipw[l]^T     (R x 4096, K=1024)
      gemm_mfma<<<dim3(R / 128, XZ_LD / 128), 256, 0, stream>>>(
          hnb, D_MODEL, ipw_b + (size_t)l * XZ_LD * D_MODEL, D_MODEL,
          nullptr, xz, XZ_LD, nullptr, 0, R, XZ_LD, D_MODEL, 0);

      conv_silu<<<dim3(D_INNER / 256, L_SEQ, bc), 256, 0, stream>>>(
          xz, cw + (size_t)l * D_INNER * D_CONV, cb + (size_t)l * D_INNER,
          xc, xcb);

      // proj = xc @ xpw[l]^T   (R x 96, K=2048), fp32 + bf16 outputs
      gemm_mfma<<<dim3(R / 128, 1), 256, 0, stream>>>(
          xcb, D_INNER, xpw_b + (size_t)l * PROJ_N * D_INNER, D_INNER,
          nullptr, proj, PROJ_N, projb, PROJ_N, R, PROJ_N, D_INNER, 0);

      // dt = softplus(proj[:,:64] @ dtw[l]^T + dtb[l]) -> xm half of xz
      gemm_mfma<<<dim3(R / 128, D_INNER / 128), 256, 0, stream>>>(
          projb, PROJ_N, dtw_b + (size_t)l * D_INNER * DT_RANK, DT_RANK,
          dtb + (size_t)l * D_INNER, xz, XZ_LD, nullptr, 0,
          R, D_INNER, DT_RANK, 1);

      // selective scan + D-skip + silu(z); writes y bf16 into xcb
      scan2<<<dim3(D_INNER / 16, bc), 256, 0, stream>>>(
          xz, xc, proj, Alog + (size_t)l * D_INNER * D_STATE,
          Dp + (size_t)l * D_INNER, xcb);

      // hs = y @ opw[l]^T      (R x 1024, K=2048)
      gemm_mfma<<<dim3(R / 128, D_MODEL / 128), 256, 0, stream>>>(
          xcb, D_INNER, opw_b + (size_t)l * D_MODEL * D_INNER, D_INNER,
          nullptr, hs, D_MODEL, nullptr, 0, R, D_MODEL, D_INNER, 0);
    }

    pool_norm<<<bc * TT, 256, 0, stream>>>(hs, res, normfw, out, b0);
  }
}

// Round 4
// 11939.653 us; speedup vs baseline: 3.2904x; 1.8199x over previous
//
#include <hip/hip_runtime.h>
#include <hip/hip_bf16.h>
#include <math.h>

#define D_MODEL 1024
#define D_INNER 2048
#define D_STATE 16
#define D_CONV 4
#define DT_RANK 64
#define N_LAYER 8
#define INPUT_DIM 256
#define BATCH 16
#define TT 64
#define S_IN 13
#define SEQ_S 16                 // S_IN + 3
#define L_SEQ 1024               // TT * SEQ_S
#define XZ_LD (2 * D_INNER)      // 4096
#define PROJ_N 96                // DT_RANK + 2*D_STATE
#define EPS 1e-5f
#define T_TILE 32                // scan time-tile

typedef __attribute__((ext_vector_type(8))) short short8;   // 8 x bf16 (4 VGPRs)
typedef __attribute__((ext_vector_type(4))) float f32x4;    // MFMA acc

// fp32 -> bf16 bits, round-to-nearest-even
__device__ __forceinline__ unsigned short f2bu(float x) {
  unsigned int u = __float_as_uint(x);
  unsigned int r = (u + 0x7fffu + ((u >> 16) & 1u)) >> 16;
  return (unsigned short)r;
}

__device__ __forceinline__ void gload_lds16(const void* g, void* l) {
  __builtin_amdgcn_global_load_lds(
      (const __attribute__((address_space(1))) void*)g,
      (__attribute__((address_space(3))) void*)l, 16, 0, 0);
}

// ---------------------------------------------------------------------------
// bf16 MFMA GEMM: C[M,N] = A[M,K](bf16) @ W[N,K](bf16)^T (+bias)(+act)
// 128x128 tile, BK=32, 4 waves x (4x4 of 16x16x32 MFMA), global_load_lds.
// K-split: gridDim.z slices K into kLen chunks; slice z writes to
// C + z*cPartStride (partials; caller must combine). kLen % 32 == 0.
// act: 0 none, 1 softplus. Cb (optional) = bf16 copy of C.
// ---------------------------------------------------------------------------
__global__ __launch_bounds__(256) void gemm_mfma(
    const unsigned short* __restrict__ A, int lda,
    const unsigned short* __restrict__ W, int ldw,
    const float* __restrict__ bias,
    float* __restrict__ C, int ldc, size_t cPartStride,
    unsigned short* __restrict__ Cb, int ldcb,
    int M, int N, int kLen, int act)
{
  __shared__ unsigned short As[128 * 32];  // 8 KB
  __shared__ unsigned short Ws[128 * 32];  // 8 KB
  const int tid  = threadIdx.x;
  const int wave = tid >> 6;
  const int lane = tid & 63;
  const int m0 = blockIdx.x * 128;
  const int n0 = blockIdx.y * 128;
  const int wm = (wave & 1) * 64;
  const int wn = (wave >> 1) * 64;
  const int kStart = blockIdx.z * kLen;
  C += (size_t)blockIdx.z * cPartStride;

  const int srow = (lane >> 2);
  const int scol = (lane & 3) * 8;         // bf16 elements

  f32x4 acc[4][4] = {};

  for (int k0 = kStart; k0 < kStart + kLen; k0 += 32) {
#pragma unroll
    for (int i = 0; i < 2; ++i) {
      int rowA = m0 + wave * 32 + i * 16 + srow;
      if (rowA > M - 1) rowA = M - 1;
      gload_lds16(A + (size_t)rowA * lda + k0 + scol,
                  &As[(wave * 32 + i * 16) * 32]);
      int rowW = n0 + wave * 32 + i * 16 + srow;
      if (rowW > N - 1) rowW = N - 1;
      gload_lds16(W + (size_t)rowW * ldw + k0 + scol,
                  &Ws[(wave * 32 + i * 16) * 32]);
    }
    __syncthreads();

    short8 af[4], bf[4];
#pragma unroll
    for (int mi = 0; mi < 4; ++mi)
      af[mi] = *(const short8*)&As[(wm + mi * 16 + (lane & 15)) * 32 + (lane >> 4) * 8];
#pragma unroll
    for (int ni = 0; ni < 4; ++ni)
      bf[ni] = *(const short8*)&Ws[(wn + ni * 16 + (lane & 15)) * 32 + (lane >> 4) * 8];
#pragma unroll
    for (int mi = 0; mi < 4; ++mi)
#pragma unroll
      for (int ni = 0; ni < 4; ++ni)
        acc[mi][ni] = __builtin_amdgcn_mfma_f32_16x16x32_bf16(
            af[mi], bf[ni], acc[mi][ni], 0, 0, 0);
    __syncthreads();
  }

  // epilogue: C/D layout col=lane&15, row=(lane>>4)*4+r   [m89-verified]
#pragma unroll
  for (int mi = 0; mi < 4; ++mi) {
#pragma unroll
    for (int ni = 0; ni < 4; ++ni) {
      const int col = n0 + wn + ni * 16 + (lane & 15);
      if (col >= N) continue;
#pragma unroll
      for (int r = 0; r < 4; ++r) {
        const int row = m0 + wm + mi * 16 + (lane >> 4) * 4 + r;
        if (row >= M) continue;
        float v = acc[mi][ni][r];
        if (bias) v += bias[col];
        if (act == 1) v = (v > 20.f) ? v : log1pf(__expf(v));  // softplus
        C[(size_t)row * ldc + col] = v;
        if (Cb) Cb[(size_t)row * ldcb + col] = f2bu(v);
      }
    }
  }
}

// ---------------------------------------------------------------------------
// Sum 4 K-split partials of x_proj -> proj fp32 + projb bf16
// ---------------------------------------------------------------------------
__global__ __launch_bounds__(256) void xproj_combine(
    const float* __restrict__ part, float* __restrict__ proj,
    unsigned short* __restrict__ projb, int n4, size_t stride4)
{
  int i = blockIdx.x * 256 + threadIdx.x;
  if (i >= n4) return;
  float4 a = ((const float4*)part)[i];
  float4 b = ((const float4*)part)[i + stride4];
  float4 c = ((const float4*)part)[i + 2 * stride4];
  float4 d = ((const float4*)part)[i + 3 * stride4];
  float4 v = make_float4(a.x + b.x + c.x + d.x, a.y + b.y + c.y + d.y,
                         a.z + b.z + c.z + d.z, a.w + b.w + c.w + d.w);
  ((float4*)proj)[i] = v;
  ushort4 o;
  o.x = f2bu(v.x); o.y = f2bu(v.y); o.z = f2bu(v.z); o.w = f2bu(v.w);
  ((ushort4*)projb)[i] = o;
}

// ---------------------------------------------------------------------------
// generic fp32 -> bf16 conversion (float4 vectorized)
// ---------------------------------------------------------------------------
__global__ __launch_bounds__(256) void cvt_bf16(
    const float* __restrict__ in, unsigned short* __restrict__ out, int n4)
{
  int i = blockIdx.x * 256 + threadIdx.x;
  if (i < n4) {
    float4 v = ((const float4*)in)[i];
    ushort4 o;
    o.x = f2bu(v.x); o.y = f2bu(v.y); o.z = f2bu(v.z); o.w = f2bu(v.w);
    ((ushort4*)out)[i] = o;
  }
}

// ---------------------------------------------------------------------------
__device__ __forceinline__ float block_reduce_sum_256(float v)
{
  __shared__ float red[4];
#pragma unroll
  for (int off = 32; off > 0; off >>= 1) v += __shfl_xor(v, off, 64);
  const int tid = threadIdx.x;
  if ((tid & 63) == 0) red[tid >> 6] = v;
  __syncthreads();
  return red[0] + red[1] + red[2] + red[3];
}

// ---------------------------------------------------------------------------
// Token assembly: hs = concat([cls, h, 0, 0]) + pe ; res = 0
// ---------------------------------------------------------------------------
__global__ __launch_bounds__(256) void seq_build(
    const float* __restrict__ hflat, const float* __restrict__ cls,
    float* __restrict__ hs, float* __restrict__ res)
{
  const int row = blockIdx.x;            // b_local*1024 + l
  const int bl = row >> 10;
  const int l = row & (L_SEQ - 1);
  const int t = l >> 4;
  const int s = l & 15;
  const int tid = threadIdx.x;

  float4 v;
  if (s == 0) {
    v = ((const float4*)cls)[tid];
  } else if (s <= S_IN) {
    const size_t hrow = ((size_t)(bl * TT + t) * S_IN + (s - 1)) * D_MODEL;
    v = ((const float4*)(hflat + hrow))[tid];
  } else {
    v = make_float4(0.f, 0.f, 0.f, 0.f);
  }

  const float cexp = -logf(10000.f) / (float)D_MODEL;
  float pe[4];
#pragma unroll
  for (int j = 0; j < 4; ++j) {
    int d = tid * 4 + j;
    int i2 = d & ~1;
    float ang = (float)t * expf((float)i2 * cexp);
    pe[j] = (d & 1) ? cosf(ang) : sinf(ang);
  }
  v.x += pe[0]; v.y += pe[1]; v.z += pe[2]; v.w += pe[3];

  const size_t base = (size_t)row * D_MODEL;
  ((float4*)(hs + base))[tid] = v;
  ((float4*)(res + base))[tid] = make_float4(0.f, 0.f, 0.f, 0.f);
}

// ---------------------------------------------------------------------------
// res += hs ; hn(bf16) = rmsnorm(res) * w
// ---------------------------------------------------------------------------
__global__ __launch_bounds__(256) void add_rmsnorm(
    float* __restrict__ res, const float* __restrict__ hs,
    unsigned short* __restrict__ hnb, const float* __restrict__ w)
{
  const int row = blockIdx.x;
  const int tid = threadIdx.x;
  const size_t base = (size_t)row * D_MODEL;
  float4 r = ((const float4*)(res + base))[tid];
  float4 h = ((const float4*)(hs + base))[tid];
  r.x += h.x; r.y += h.y; r.z += h.z; r.w += h.w;
  ((float4*)(res + base))[tid] = r;
  float ss = r.x * r.x + r.y * r.y + r.z * r.z + r.w * r.w;
  ss = block_reduce_sum_256(ss);
  const float scale = rsqrtf(ss * (1.f / (float)D_MODEL) + EPS);
  float4 wv = ((const float4*)w)[tid];
  ushort4 o;
  o.x = f2bu(r.x * scale * wv.x);
  o.y = f2bu(r.y * scale * wv.y);
  o.z = f2bu(r.z * scale * wv.z);
  o.w = f2bu(r.w * scale * wv.w);
  ((ushort4*)(hnb + base))[tid] = o;
}

// ---------------------------------------------------------------------------
// Depthwise causal conv (K=4) + silu; writes xc fp32 + xcb bf16
// ---------------------------------------------------------------------------
__global__ __launch_bounds__(256) void conv_silu(
    const float* __restrict__ xz, const float* __restrict__ cw,
    const float* __restrict__ cb, float* __restrict__ xc,
    unsigned short* __restrict__ xcb)
{
  const int c = blockIdx.x * 256 + threadIdx.x;
  const int t = blockIdx.y;
  const int bl = blockIdx.z;
  const size_t row = (size_t)bl * L_SEQ + t;

  const float w0 = cw[c * D_CONV + 0];
  const float w1 = cw[c * D_CONV + 1];
  const float w2 = cw[c * D_CONV + 2];
  const float w3 = cw[c * D_CONV + 3];

  float acc = cb[c];
  if (t >= 3) acc = fmaf(w0, xz[(row - 3) * XZ_LD + c], acc);
  if (t >= 2) acc = fmaf(w1, xz[(row - 2) * XZ_LD + c], acc);
  if (t >= 1) acc = fmaf(w2, xz[(row - 1) * XZ_LD + c], acc);
  acc = fmaf(w3, xz[row * XZ_LD + c], acc);

  acc = acc / (1.f + __expf(-acc));      // silu
  xc[row * D_INNER + c] = acc;
  xcb[row * D_INNER + c] = f2bu(acc);
}

// ---------------------------------------------------------------------------
// scan3: thread per (ch,s), 16 lanes/channel, double-buffered LDS time-tiles.
// Per block: 16 channels, T_TILE steps of dt/z/u/B/C staged via
// global_load_lds width-16 one tile ahead. LDS 20 KB -> 8 blocks/CU cap;
// grid 128*bc blocks -> 4/CU at bc=8.
// ---------------------------------------------------------------------------
__device__ __forceinline__ void scan_stage(
    const float* xz, const float* xc, const float* proj,
    size_t base, int t0, int ch0, int wave, int lane,
    float (*sdt)[16], float (*sz)[16], float (*su)[16],
    float (*sB)[16], float (*sC)[16])
{
  const int tr = lane >> 2;            // step within 16-row half
  const int c  = (lane & 3) * 4;       // 4-float column chunk
  // each issue: 64 lanes x 16 B = one 16x16 fp32 tile
  if (wave == 0) {
    gload_lds16(xz + (base + t0 + tr) * XZ_LD + ch0 + c,               &sdt[0][0]);
    gload_lds16(xz + (base + t0 + 16 + tr) * XZ_LD + ch0 + c,          &sdt[16][0]);
    gload_lds16(proj + (base + t0 + tr) * PROJ_N + 80 + c,             &sC[0][0]);
  } else if (wave == 1) {
    gload_lds16(xz + (base + t0 + tr) * XZ_LD + D_INNER + ch0 + c,     &sz[0][0]);
    gload_lds16(xz + (base + t0 + 16 + tr) * XZ_LD + D_INNER + ch0 + c,&sz[16][0]);
    gload_lds16(proj + (base + t0 + 16 + tr) * PROJ_N + 80 + c,        &sC[16][0]);
  } else if (wave == 2) {
    gload_lds16(xc + (base + t0 + tr) * D_INNER + ch0 + c,             &su[0][0]);
    gload_lds16(xc + (base + t0 + 16 + tr) * D_INNER + ch0 + c,        &su[16][0]);
  } else {
    gload_lds16(proj + (base + t0 + tr) * PROJ_N + 64 + c,             &sB[0][0]);
    gload_lds16(proj + (base + t0 + 16 + tr) * PROJ_N + 64 + c,        &sB[16][0]);
  }
}

__global__ __launch_bounds__(256) void scan3(
    const float* __restrict__ xz, const float* __restrict__ xc,
    const float* __restrict__ proj,
    const float* __restrict__ Alog, const float* __restrict__ Dp,
    unsigned short* __restrict__ yb)
{
  __shared__ float sdt[2][T_TILE][16];
  __shared__ float sz [2][T_TILE][16];
  __shared__ float su [2][T_TILE][16];
  __shared__ float sB [2][T_TILE][16];
  __shared__ float sC [2][T_TILE][16];

  const int tid = threadIdx.x;
  const int wave = tid >> 6;
  const int lane = tid & 63;
  const int s  = tid & 15;             // state
  const int cl = tid >> 4;             // channel within block (0..15)
  const int ch0 = blockIdx.x * 16;
  const int ch = ch0 + cl;
  const int bl = blockIdx.y;
  const size_t base = (size_t)bl * L_SEQ;

  const float As = -__expf(Alog[(size_t)ch * D_STATE + s]);
  const float Dv = Dp[ch];
  float h = 0.f;

  scan_stage(xz, xc, proj, base, 0, ch0, wave, lane,
             sdt[0], sz[0], su[0], sB[0], sC[0]);

  const int NT = L_SEQ / T_TILE;       // 32 tiles
  for (int tile = 0; tile < NT; ++tile) {
    const int bf = tile & 1;
    __syncthreads();                   // drains this wave's staging loads
    if (tile + 1 < NT) {
      const int nb = bf ^ 1;
      scan_stage(xz, xc, proj, base, (tile + 1) * T_TILE, ch0, wave, lane,
                 sdt[nb], sz[nb], su[nb], sB[nb], sC[nb]);
    }
    const int t0 = tile * T_TILE;
#pragma unroll 8
    for (int tt = 0; tt < T_TILE; ++tt) {
      const float dtv = sdt[bf][tt][cl];
      const float Bv  = sB[bf][tt][s];
      const float Cv  = sC[bf][tt][s];
      const float u   = su[bf][tt][cl];
      const float dA = __expf(dtv * As);
      h = fmaf(dA, h, dtv * u * Bv);
      float p = h * Cv;
      p += __shfl_xor(p, 1, 64);
      p += __shfl_xor(p, 2, 64);
      p += __shfl_xor(p, 4, 64);
      p += __shfl_xor(p, 8, 64);
      if (s == 0) {
        const float zv = sz[bf][tt][cl];
        const float yv = fmaf(Dv, u, p);
        const float g = zv / (1.f + __expf(-zv));   // silu(z)
        yb[(base + t0 + tt) * D_INNER + ch] = f2bu(yv * g);
      }
    }
  }
}

// ---------------------------------------------------------------------------
// Final pooled rmsnorm on cls rows
// ---------------------------------------------------------------------------
__global__ __launch_bounds__(256) void pool_norm(
    const float* __restrict__ hs, const float* __restrict__ res,
    const float* __restrict__ w, float* __restrict__ out, int b0)
{
  const int idx = blockIdx.x;                      // b_local*64 + t
  const int bl = idx >> 6;
  const int t = idx & 63;
  const size_t base = ((size_t)bl * L_SEQ + (size_t)t * SEQ_S) * D_MODEL;
  const int tid = threadIdx.x;
  float4 h = ((const float4*)(hs + base))[tid];
  float4 r = ((const float4*)(res + base))[tid];
  float4 v = make_float4(h.x + r.x, h.y + r.y, h.z + r.z, h.w + r.w);
  float ss = v.x * v.x + v.y * v.y + v.z * v.z + v.w * v.w;
  ss = block_reduce_sum_256(ss);
  const float scale = rsqrtf(ss * (1.f / (float)D_MODEL) + EPS);
  float4 wv = ((const float4*)w)[tid];
  float4 o = make_float4(v.x * scale * wv.x, v.y * scale * wv.y,
                         v.z * scale * wv.z, v.w * scale * wv.w);
  const size_t orow = (size_t)((b0 + bl) * TT + t) * D_MODEL;
  ((float4*)(out + orow))[tid] = o;
}

// ---------------------------------------------------------------------------
extern "C" void kernel_launch(void* const* d_in, const int* in_sizes, int n_in,
                              void* d_out, int out_size, void* d_ws, size_t ws_size,
                              hipStream_t stream)
{
  const float* x      = (const float*)d_in[0];
  // d_in[1] = tt (int scalar, == 64): compiled in as TT
  const float* w_in   = (const float*)d_in[2];
  const float* b_in   = (const float*)d_in[3];
  const float* cls    = (const float*)d_in[4];
  const float* norm_w = (const float*)d_in[5];
  const float* ipw    = (const float*)d_in[6];
  const float* cw     = (const float*)d_in[7];
  const float* cb     = (const float*)d_in[8];
  const float* xpw    = (const float*)d_in[9];
  const float* dtw    = (const float*)d_in[10];
  const float* dtb    = (const float*)d_in[11];
  const float* Alog   = (const float*)d_in[12];
  const float* Dp     = (const float*)d_in[13];
  const float* opw    = (const float*)d_in[14];
  const float* normfw = (const float*)d_in[15];
  float* out = (float*)d_out;

  // ---- bf16 weight/x region (elements) ----
  const size_t N_WIN = (size_t)D_MODEL * INPUT_DIM;
  const size_t N_IPW = (size_t)N_LAYER * XZ_LD * D_MODEL;
  const size_t N_XPW = (size_t)N_LAYER * PROJ_N * D_INNER;
  const size_t N_DTW = (size_t)N_LAYER * D_INNER * DT_RANK;
  const size_t N_OPW = (size_t)N_LAYER * D_MODEL * D_INNER;
  const size_t N_XB  = (size_t)BATCH * TT * S_IN * INPUT_DIM;
  const size_t N_BF  = N_WIN + N_IPW + N_XPW + N_DTW + N_OPW + N_XB;

  // per-batch activation bytes (x_proj partials alias the dead hs window):
  const size_t perB = (size_t)L_SEQ * (8288 * 4 + 3168 * 2);
  int bc = 0;
  for (int c = 16; c >= 1; c >>= 1)
    if (N_BF * 2 + perB * (size_t)c <= ws_size) { bc = c; break; }
  if (bc == 0) return;

  const int R = bc * L_SEQ;

  unsigned short* w_in_b = (unsigned short*)d_ws;
  unsigned short* ipw_b  = w_in_b + N_WIN;
  unsigned short* xpw_b  = ipw_b + N_IPW;
  unsigned short* dtw_b  = xpw_b + N_XPW;
  unsigned short* opw_b  = dtw_b + N_DTW;
  unsigned short* x_b    = opw_b + N_OPW;
  float* res  = (float*)(x_b + N_XB);
  float* hs   = res + (size_t)R * D_MODEL;
  float* xz   = hs + (size_t)R * D_MODEL;
  float* xc   = xz + (size_t)R * XZ_LD;
  float* proj = xc + (size_t)R * D_INNER;
  unsigned short* hnb   = (unsigned short*)(proj + (size_t)R * PROJ_N);
  unsigned short* xcb   = hnb + (size_t)R * D_MODEL;   // xc bf16, then y bf16
  unsigned short* projb = xcb + (size_t)R * D_INNER;
  // x_proj K-split partials live in the dead hs window (R*384 <= R*1024 floats)
  float* ppart = hs;

  // ---- weight + x conversion (once per launch; ws re-poisoned each call) ----
  cvt_bf16<<<(int)((N_WIN/4 + 255)/256), 256, 0, stream>>>(w_in, w_in_b, (int)(N_WIN/4));
  cvt_bf16<<<(int)((N_IPW/4 + 255)/256), 256, 0, stream>>>(ipw, ipw_b, (int)(N_IPW/4));
  cvt_bf16<<<(int)((N_XPW/4 + 255)/256), 256, 0, stream>>>(xpw, xpw_b, (int)(N_XPW/4));
  cvt_bf16<<<(int)((N_DTW/4 + 255)/256), 256, 0, stream>>>(dtw, dtw_b, (int)(N_DTW/4));
  cvt_bf16<<<(int)((N_OPW/4 + 255)/256), 256, 0, stream>>>(opw, opw_b, (int)(N_OPW/4));
  cvt_bf16<<<(int)((N_XB/4  + 255)/256), 256, 0, stream>>>(x,   x_b,   (int)(N_XB/4));

  for (int b0 = 0; b0 < BATCH; b0 += bc) {
    // 1. input projection: hflat(=xz region) = x_chunk @ w_in^T + b_in
    const int Mx = bc * TT * S_IN;
    float* hflat = xz;
    gemm_mfma<<<dim3((Mx + 127) / 128, D_MODEL / 128), 256, 0, stream>>>(
        x_b + (size_t)b0 * TT * S_IN * INPUT_DIM, INPUT_DIM,
        w_in_b, INPUT_DIM, b_in, hflat, D_MODEL, 0, nullptr, 0,
        Mx, D_MODEL, INPUT_DIM, 0);

    // 2. token assembly + positional encoding
    seq_build<<<R, 256, 0, stream>>>(hflat, cls, hs, res);

    for (int l = 0; l < N_LAYER; ++l) {
      add_rmsnorm<<<R, 256, 0, stream>>>(res, hs, hnb,
          norm_w + (size_t)l * D_MODEL);

      // xz = hn @ ipw[l]^T     (R x 4096, K=1024)
      gemm_mfma<<<dim3(R / 128, XZ_LD / 128), 256, 0, stream>>>(
          hnb, D_MODEL, ipw_b + (size_t)l * XZ_LD * D_MODEL, D_MODEL,
          nullptr, xz, XZ_LD, 0, nullptr, 0, R, XZ_LD, D_MODEL, 0);

      conv_silu<<<dim3(D_INNER / 256, L_SEQ, bc), 256, 0, stream>>>(
          xz, cw + (size_t)l * D_INNER * D_CONV, cb + (size_t)l * D_INNER,
          xc, xcb);

      // x_proj partials: 4-way K-split over K=2048 (hs window is dead here)
      gemm_mfma<<<dim3(R / 128, 1, 4), 256, 0, stream>>>(
          xcb, D_INNER, xpw_b + (size_t)l * PROJ_N * D_INNER, D_INNER,
          nullptr, ppart, PROJ_N, (size_t)R * PROJ_N, nullptr, 0,
          R, PROJ_N, 512, 0);
      xproj_combine<<<(R * PROJ_N / 4 + 255) / 256, 256, 0, stream>>>(
          ppart, proj, projb, R * PROJ_N / 4, (size_t)R * PROJ_N / 4);

      // dt = softplus(proj[:,:64] @ dtw[l]^T + dtb[l]) -> xm half of xz
      gemm_mfma<<<dim3(R / 128, D_INNER / 128), 256, 0, stream>>>(
          projb, PROJ_N, dtw_b + (size_t)l * D_INNER * DT_RANK, DT_RANK,
          dtb + (size_t)l * D_INNER, xz, XZ_LD, 0, nullptr, 0,
          R, D_INNER, 64, 1);

      // selective scan + D-skip + silu(z); writes y bf16 into xcb
      scan3<<<dim3(D_INNER / 16, bc), 256, 0, stream>>>(
          xz, xc, proj, Alog + (size_t)l * D_INNER * D_STATE,
          Dp + (size_t)l * D_INNER, xcb);

      // hs = y @ opw[l]^T      (R x 1024, K=2048)
      gemm_mfma<<<dim3(R / 128, D_MODEL / 128), 256, 0, stream>>>(
          xcb, D_INNER, opw_b + (size_t)l * D_MODEL * D_INNER, D_INNER,
          nullptr, hs, D_MODEL, 0, nullptr, 0, R, D_MODEL, D_INNER, 0);
    }

    pool_norm<<<bc * TT, 256, 0, stream>>>(hs, res, normfw, out, b0);
  }
}

// Round 5
// 9966.431 us; speedup vs baseline: 3.9419x; 1.1980x over previous
//
#include <hip/hip_runtime.h>
#include <hip/hip_bf16.h>
#include <math.h>

#define D_MODEL 1024
#define D_INNER 2048
#define D_STATE 16
#define D_CONV 4
#define DT_RANK 64
#define N_LAYER 8
#define INPUT_DIM 256
#define BATCH 16
#define TT 64
#define S_IN 13
#define SEQ_S 16                 // S_IN + 3
#define L_SEQ 1024               // TT * SEQ_S
#define XZ_LD (2 * D_INNER)      // 4096
#define PROJ_N 96                // DT_RANK + 2*D_STATE
#define EPS 1e-5f

typedef __attribute__((ext_vector_type(8))) short short8;   // 8 x bf16 (4 VGPRs)
typedef __attribute__((ext_vector_type(4))) float f32x4;    // MFMA acc

// fp32 -> bf16 bits, round-to-nearest-even
__device__ __forceinline__ unsigned short f2bu(float x) {
  unsigned int u = __float_as_uint(x);
  unsigned int r = (u + 0x7fffu + ((u >> 16) & 1u)) >> 16;
  return (unsigned short)r;
}

__device__ __forceinline__ void gload_lds16(const void* g, void* l) {
  __builtin_amdgcn_global_load_lds(
      (const __attribute__((address_space(1))) void*)g,
      (__attribute__((address_space(3))) void*)l, 16, 0, 0);
}

// ---------------------------------------------------------------------------
// bf16 MFMA GEMM: C[M,N] = A[M,K](bf16) @ W[N,K](bf16)^T (+bias)(+act)
// 128x128 tile, BK=32, 4 waves x (4x4 of 16x16x32 MFMA), global_load_lds.
// K-split: gridDim.z slices K into kLen chunks; slice z writes to
// C + z*cPartStride (partials; caller must combine). kLen % 32 == 0.
// act: 0 none, 1 softplus. Cb (optional) = bf16 copy of C.
// ---------------------------------------------------------------------------
__global__ __launch_bounds__(256) void gemm_mfma(
    const unsigned short* __restrict__ A, int lda,
    const unsigned short* __restrict__ W, int ldw,
    const float* __restrict__ bias,
    float* __restrict__ C, int ldc, size_t cPartStride,
    unsigned short* __restrict__ Cb, int ldcb,
    int M, int N, int kLen, int act)
{
  __shared__ unsigned short As[128 * 32];  // 8 KB
  __shared__ unsigned short Ws[128 * 32];  // 8 KB
  const int tid  = threadIdx.x;
  const int wave = tid >> 6;
  const int lane = tid & 63;
  const int m0 = blockIdx.x * 128;
  const int n0 = blockIdx.y * 128;
  const int wm = (wave & 1) * 64;
  const int wn = (wave >> 1) * 64;
  const int kStart = blockIdx.z * kLen;
  C += (size_t)blockIdx.z * cPartStride;

  const int srow = (lane >> 2);
  const int scol = (lane & 3) * 8;         // bf16 elements

  f32x4 acc[4][4] = {};

  for (int k0 = kStart; k0 < kStart + kLen; k0 += 32) {
#pragma unroll
    for (int i = 0; i < 2; ++i) {
      int rowA = m0 + wave * 32 + i * 16 + srow;
      if (rowA > M - 1) rowA = M - 1;
      gload_lds16(A + (size_t)rowA * lda + k0 + scol,
                  &As[(wave * 32 + i * 16) * 32]);
      int rowW = n0 + wave * 32 + i * 16 + srow;
      if (rowW > N - 1) rowW = N - 1;
      gload_lds16(W + (size_t)rowW * ldw + k0 + scol,
                  &Ws[(wave * 32 + i * 16) * 32]);
    }
    __syncthreads();

    short8 af[4], bf[4];
#pragma unroll
    for (int mi = 0; mi < 4; ++mi)
      af[mi] = *(const short8*)&As[(wm + mi * 16 + (lane & 15)) * 32 + (lane >> 4) * 8];
#pragma unroll
    for (int ni = 0; ni < 4; ++ni)
      bf[ni] = *(const short8*)&Ws[(wn + ni * 16 + (lane & 15)) * 32 + (lane >> 4) * 8];
#pragma unroll
    for (int mi = 0; mi < 4; ++mi)
#pragma unroll
      for (int ni = 0; ni < 4; ++ni)
        acc[mi][ni] = __builtin_amdgcn_mfma_f32_16x16x32_bf16(
            af[mi], bf[ni], acc[mi][ni], 0, 0, 0);
    __syncthreads();
  }

  // epilogue: C/D layout col=lane&15, row=(lane>>4)*4+r   [m89-verified]
#pragma unroll
  for (int mi = 0; mi < 4; ++mi) {
#pragma unroll
    for (int ni = 0; ni < 4; ++ni) {
      const int col = n0 + wn + ni * 16 + (lane & 15);
      if (col >= N) continue;
#pragma unroll
      for (int r = 0; r < 4; ++r) {
        const int row = m0 + wm + mi * 16 + (lane >> 4) * 4 + r;
        if (row >= M) continue;
        float v = acc[mi][ni][r];
        if (bias) v += bias[col];
        if (act == 1) v = (v > 20.f) ? v : log1pf(__expf(v));  // softplus
        C[(size_t)row * ldc + col] = v;
        if (Cb) Cb[(size_t)row * ldcb + col] = f2bu(v);
      }
    }
  }
}

// ---------------------------------------------------------------------------
// Sum 4 K-split partials of x_proj -> proj fp32 + projb bf16
// ---------------------------------------------------------------------------
__global__ __launch_bounds__(256) void xproj_combine(
    const float* __restrict__ part, float* __restrict__ proj,
    unsigned short* __restrict__ projb, int n4, size_t stride4)
{
  int i = blockIdx.x * 256 + threadIdx.x;
  if (i >= n4) return;
  float4 a = ((const float4*)part)[i];
  float4 b = ((const float4*)part)[i + stride4];
  float4 c = ((const float4*)part)[i + 2 * stride4];
  float4 d = ((const float4*)part)[i + 3 * stride4];
  float4 v = make_float4(a.x + b.x + c.x + d.x, a.y + b.y + c.y + d.y,
                         a.z + b.z + c.z + d.z, a.w + b.w + c.w + d.w);
  ((float4*)proj)[i] = v;
  ushort4 o;
  o.x = f2bu(v.x); o.y = f2bu(v.y); o.z = f2bu(v.z); o.w = f2bu(v.w);
  ((ushort4*)projb)[i] = o;
}

// ---------------------------------------------------------------------------
// generic fp32 -> bf16 conversion (float4 vectorized)
// ---------------------------------------------------------------------------
__global__ __launch_bounds__(256) void cvt_bf16(
    const float* __restrict__ in, unsigned short* __restrict__ out, int n4)
{
  int i = blockIdx.x * 256 + threadIdx.x;
  if (i < n4) {
    float4 v = ((const float4*)in)[i];
    ushort4 o;
    o.x = f2bu(v.x); o.y = f2bu(v.y); o.z = f2bu(v.z); o.w = f2bu(v.w);
    ((ushort4*)out)[i] = o;
  }
}

// ---------------------------------------------------------------------------
__device__ __forceinline__ float block_reduce_sum_256(float v)
{
  __shared__ float red[4];
#pragma unroll
  for (int off = 32; off > 0; off >>= 1) v += __shfl_xor(v, off, 64);
  const int tid = threadIdx.x;
  if ((tid & 63) == 0) red[tid >> 6] = v;
  __syncthreads();
  return red[0] + red[1] + red[2] + red[3];
}

// ---------------------------------------------------------------------------
// Token assembly: hs = concat([cls, h, 0, 0]) + pe ; res = 0
// ---------------------------------------------------------------------------
__global__ __launch_bounds__(256) void seq_build(
    const float* __restrict__ hflat, const float* __restrict__ cls,
    float* __restrict__ hs, float* __restrict__ res)
{
  const int row = blockIdx.x;            // b_local*1024 + l
  const int bl = row >> 10;
  const int l = row & (L_SEQ - 1);
  const int t = l >> 4;
  const int s = l & 15;
  const int tid = threadIdx.x;

  float4 v;
  if (s == 0) {
    v = ((const float4*)cls)[tid];
  } else if (s <= S_IN) {
    const size_t hrow = ((size_t)(bl * TT + t) * S_IN + (s - 1)) * D_MODEL;
    v = ((const float4*)(hflat + hrow))[tid];
  } else {
    v = make_float4(0.f, 0.f, 0.f, 0.f);
  }

  const float cexp = -logf(10000.f) / (float)D_MODEL;
  float pe[4];
#pragma unroll
  for (int j = 0; j < 4; ++j) {
    int d = tid * 4 + j;
    int i2 = d & ~1;
    float ang = (float)t * expf((float)i2 * cexp);
    pe[j] = (d & 1) ? cosf(ang) : sinf(ang);
  }
  v.x += pe[0]; v.y += pe[1]; v.z += pe[2]; v.w += pe[3];

  const size_t base = (size_t)row * D_MODEL;
  ((float4*)(hs + base))[tid] = v;
  ((float4*)(res + base))[tid] = make_float4(0.f, 0.f, 0.f, 0.f);
}

// ---------------------------------------------------------------------------
// res += hs ; hn(bf16) = rmsnorm(res) * w
// ---------------------------------------------------------------------------
__global__ __launch_bounds__(256) void add_rmsnorm(
    float* __restrict__ res, const float* __restrict__ hs,
    unsigned short* __restrict__ hnb, const float* __restrict__ w)
{
  const int row = blockIdx.x;
  const int tid = threadIdx.x;
  const size_t base = (size_t)row * D_MODEL;
  float4 r = ((const float4*)(res + base))[tid];
  float4 h = ((const float4*)(hs + base))[tid];
  r.x += h.x; r.y += h.y; r.z += h.z; r.w += h.w;
  ((float4*)(res + base))[tid] = r;
  float ss = r.x * r.x + r.y * r.y + r.z * r.z + r.w * r.w;
  ss = block_reduce_sum_256(ss);
  const float scale = rsqrtf(ss * (1.f / (float)D_MODEL) + EPS);
  float4 wv = ((const float4*)w)[tid];
  ushort4 o;
  o.x = f2bu(r.x * scale * wv.x);
  o.y = f2bu(r.y * scale * wv.y);
  o.z = f2bu(r.z * scale * wv.z);
  o.w = f2bu(r.w * scale * wv.w);
  ((ushort4*)(hnb + base))[tid] = o;
}

// ---------------------------------------------------------------------------
// Depthwise causal conv (K=4) + silu; writes xc fp32 + xcb bf16
// ---------------------------------------------------------------------------
__global__ __launch_bounds__(256) void conv_silu(
    const float* __restrict__ xz, const float* __restrict__ cw,
    const float* __restrict__ cb, float* __restrict__ xc,
    unsigned short* __restrict__ xcb)
{
  const int c = blockIdx.x * 256 + threadIdx.x;
  const int t = blockIdx.y;
  const int bl = blockIdx.z;
  const size_t row = (size_t)bl * L_SEQ + t;

  const float w0 = cw[c * D_CONV + 0];
  const float w1 = cw[c * D_CONV + 1];
  const float w2 = cw[c * D_CONV + 2];
  const float w3 = cw[c * D_CONV + 3];

  float acc = cb[c];
  if (t >= 3) acc = fmaf(w0, xz[(row - 3) * XZ_LD + c], acc);
  if (t >= 2) acc = fmaf(w1, xz[(row - 2) * XZ_LD + c], acc);
  if (t >= 1) acc = fmaf(w2, xz[(row - 1) * XZ_LD + c], acc);
  acc = fmaf(w3, xz[row * XZ_LD + c], acc);

  acc = acc / (1.f + __expf(-acc));      // silu
  xc[row * D_INNER + c] = acc;
  xcb[row * D_INNER + c] = f2bu(acc);
}

// ---------------------------------------------------------------------------
// scan4: 4 states/lane, 4 lanes/channel (wave = 16 channels). No LDS —
// operands arrive via direct global loads, register software pipeline
// (4 rotating sets, prefetch distance 3 ~= L2 latency). Only 2 shuffles
// per step (quad reduce) vs scan3's 4 + 4 LDS reads — DS-pipe was the
// bottleneck (m-R4: 48 cyc/wave-step DS = measured 360us).
// Grid: (D_INNER/64, bc) blocks x 256 thr.
// ---------------------------------------------------------------------------
__global__ __launch_bounds__(256) void scan4(
    const float* __restrict__ xz, const float* __restrict__ xc,
    const float* __restrict__ proj,
    const float* __restrict__ Alog, const float* __restrict__ Dp,
    unsigned short* __restrict__ yb)
{
  const int tid  = threadIdx.x;
  const int lane = tid & 63;
  const int wave = tid >> 6;
  const int chl  = lane >> 2;            // channel within wave (0..15)
  const int sq   = lane & 3;             // state quad
  const int ch   = blockIdx.x * 64 + wave * 16 + chl;
  const int s0   = sq * 4;
  const int bl   = blockIdx.y;
  const size_t base = (size_t)bl * L_SEQ;

  float A[4], h[4] = {0.f, 0.f, 0.f, 0.f};
#pragma unroll
  for (int k = 0; k < 4; ++k)
    A[k] = -__expf(Alog[(size_t)ch * D_STATE + s0 + k]);
  const float Dv = Dp[ch];

  // register pipeline: 4 rotating sets, prefetch distance 3
  float pdt[4], pz[4], pu[4];
  float4 pB[4], pC[4];

#define SCAN_LOAD(slot, t)                                                    \
  {                                                                           \
    const size_t r_ = base + (size_t)(t);                                     \
    pdt[slot] = xz[r_ * XZ_LD + ch];                                          \
    pz[slot]  = xz[r_ * XZ_LD + D_INNER + ch];                                \
    pu[slot]  = xc[r_ * D_INNER + ch];                                        \
    pB[slot]  = *(const float4*)&proj[r_ * PROJ_N + DT_RANK + s0];            \
    pC[slot]  = *(const float4*)&proj[r_ * PROJ_N + DT_RANK + D_STATE + s0];  \
  }

  SCAN_LOAD(0, 0)
  SCAN_LOAD(1, 1)
  SCAN_LOAD(2, 2)

#pragma unroll 4
  for (int t = 0; t < L_SEQ; ++t) {
    const int sl = t & 3;
    int tn = t + 3;
    if (tn > L_SEQ - 1) tn = L_SEQ - 1;   // tail: harmless re-read
    SCAN_LOAD((t + 3) & 3, tn)

    const float dtv = pdt[sl];
    const float u   = pu[sl];
    const float du  = dtv * u;
    const float4 B4 = pB[sl];
    const float4 C4 = pC[sl];
    const float Bk[4] = {B4.x, B4.y, B4.z, B4.w};
    const float Ck[4] = {C4.x, C4.y, C4.z, C4.w};
    float yv = 0.f;
#pragma unroll
    for (int k = 0; k < 4; ++k) {
      const float dA = __expf(dtv * A[k]);
      h[k] = fmaf(dA, h[k], du * Bk[k]);
      yv = fmaf(h[k], Ck[k], yv);
    }
    yv += __shfl_xor(yv, 1, 64);
    yv += __shfl_xor(yv, 2, 64);
    if (sq == 0) {
      const float zv = pz[sl];
      const float g = zv / (1.f + __expf(-zv));     // silu(z)
      yb[(base + t) * D_INNER + ch] = f2bu(fmaf(Dv, u, yv) * g);
    }
  }
#undef SCAN_LOAD
}

// ---------------------------------------------------------------------------
// Final pooled rmsnorm on cls rows
// ---------------------------------------------------------------------------
__global__ __launch_bounds__(256) void pool_norm(
    const float* __restrict__ hs, const float* __restrict__ res,
    const float* __restrict__ w, float* __restrict__ out, int b0)
{
  const int idx = blockIdx.x;                      // b_local*64 + t
  const int bl = idx >> 6;
  const int t = idx & 63;
  const size_t base = ((size_t)bl * L_SEQ + (size_t)t * SEQ_S) * D_MODEL;
  const int tid = threadIdx.x;
  float4 h = ((const float4*)(hs + base))[tid];
  float4 r = ((const float4*)(res + base))[tid];
  float4 v = make_float4(h.x + r.x, h.y + r.y, h.z + r.z, h.w + r.w);
  float ss = v.x * v.x + v.y * v.y + v.z * v.z + v.w * v.w;
  ss = block_reduce_sum_256(ss);
  const float scale = rsqrtf(ss * (1.f / (float)D_MODEL) + EPS);
  float4 wv = ((const float4*)w)[tid];
  float4 o = make_float4(v.x * scale * wv.x, v.y * scale * wv.y,
                         v.z * scale * wv.z, v.w * scale * wv.w);
  const size_t orow = (size_t)((b0 + bl) * TT + t) * D_MODEL;
  ((float4*)(out + orow))[tid] = o;
}

// ---------------------------------------------------------------------------
extern "C" void kernel_launch(void* const* d_in, const int* in_sizes, int n_in,
                              void* d_out, int out_size, void* d_ws, size_t ws_size,
                              hipStream_t stream)
{
  const float* x      = (const float*)d_in[0];
  // d_in[1] = tt (int scalar, == 64): compiled in as TT
  const float* w_in   = (const float*)d_in[2];
  const float* b_in   = (const float*)d_in[3];
  const float* cls    = (const float*)d_in[4];
  const float* norm_w = (const float*)d_in[5];
  const float* ipw    = (const float*)d_in[6];
  const float* cw     = (const float*)d_in[7];
  const float* cb     = (const float*)d_in[8];
  const float* xpw    = (const float*)d_in[9];
  const float* dtw    = (const float*)d_in[10];
  const float* dtb    = (const float*)d_in[11];
  const float* Alog   = (const float*)d_in[12];
  const float* Dp     = (const float*)d_in[13];
  const float* opw    = (const float*)d_in[14];
  const float* normfw = (const float*)d_in[15];
  float* out = (float*)d_out;

  // ---- bf16 weight/x region (elements) ----
  const size_t N_WIN = (size_t)D_MODEL * INPUT_DIM;
  const size_t N_IPW = (size_t)N_LAYER * XZ_LD * D_MODEL;
  const size_t N_XPW = (size_t)N_LAYER * PROJ_N * D_INNER;
  const size_t N_DTW = (size_t)N_LAYER * D_INNER * DT_RANK;
  const size_t N_OPW = (size_t)N_LAYER * D_MODEL * D_INNER;
  const size_t N_XB  = (size_t)BATCH * TT * S_IN * INPUT_DIM;
  const size_t N_BF  = N_WIN + N_IPW + N_XPW + N_DTW + N_OPW + N_XB;

  // per-batch activation bytes (x_proj partials alias the dead hs window):
  const size_t perB = (size_t)L_SEQ * (8288 * 4 + 3168 * 2);
  int bc = 0;
  for (int c = 16; c >= 1; c >>= 1)
    if (N_BF * 2 + perB * (size_t)c <= ws_size) { bc = c; break; }
  if (bc == 0) return;

  const int R = bc * L_SEQ;

  unsigned short* w_in_b = (unsigned short*)d_ws;
  unsigned short* ipw_b  = w_in_b + N_WIN;
  unsigned short* xpw_b  = ipw_b + N_IPW;
  unsigned short* dtw_b  = xpw_b + N_XPW;
  unsigned short* opw_b  = dtw_b + N_DTW;
  unsigned short* x_b    = opw_b + N_OPW;
  float* res  = (float*)(x_b + N_XB);
  float* hs   = res + (size_t)R * D_MODEL;
  float* xz   = hs + (size_t)R * D_MODEL;
  float* xc   = xz + (size_t)R * XZ_LD;
  float* proj = xc + (size_t)R * D_INNER;
  unsigned short* hnb   = (unsigned short*)(proj + (size_t)R * PROJ_N);
  unsigned short* xcb   = hnb + (size_t)R * D_MODEL;   // xc bf16, then y bf16
  unsigned short* projb = xcb + (size_t)R * D_INNER;
  // x_proj K-split partials live in the dead hs window (R*384 <= R*1024 floats)
  float* ppart = hs;

  // ---- weight + x conversion (once per launch; ws re-poisoned each call) ----
  cvt_bf16<<<(int)((N_WIN/4 + 255)/256), 256, 0, stream>>>(w_in, w_in_b, (int)(N_WIN/4));
  cvt_bf16<<<(int)((N_IPW/4 + 255)/256), 256, 0, stream>>>(ipw, ipw_b, (int)(N_IPW/4));
  cvt_bf16<<<(int)((N_XPW/4 + 255)/256), 256, 0, stream>>>(xpw, xpw_b, (int)(N_XPW/4));
  cvt_bf16<<<(int)((N_DTW/4 + 255)/256), 256, 0, stream>>>(dtw, dtw_b, (int)(N_DTW/4));
  cvt_bf16<<<(int)((N_OPW/4 + 255)/256), 256, 0, stream>>>(opw, opw_b, (int)(N_OPW/4));
  cvt_bf16<<<(int)((N_XB/4  + 255)/256), 256, 0, stream>>>(x,   x_b,   (int)(N_XB/4));

  for (int b0 = 0; b0 < BATCH; b0 += bc) {
    // 1. input projection: hflat(=xz region) = x_chunk @ w_in^T + b_in
    const int Mx = bc * TT * S_IN;
    float* hflat = xz;
    gemm_mfma<<<dim3((Mx + 127) / 128, D_MODEL / 128), 256, 0, stream>>>(
        x_b + (size_t)b0 * TT * S_IN * INPUT_DIM, INPUT_DIM,
        w_in_b, INPUT_DIM, b_in, hflat, D_MODEL, 0, nullptr, 0,
        Mx, D_MODEL, INPUT_DIM, 0);

    // 2. token assembly + positional encoding
    seq_build<<<R, 256, 0, stream>>>(hflat, cls, hs, res);

    for (int l = 0; l < N_LAYER; ++l) {
      add_rmsnorm<<<R, 256, 0, stream>>>(res, hs, hnb,
          norm_w + (size_t)l * D_MODEL);

      // xz = hn @ ipw[l]^T     (R x 4096, K=1024)
      gemm_mfma<<<dim3(R / 128, XZ_LD / 128), 256, 0, stream>>>(
          hnb, D_MODEL, ipw_b + (size_t)l * XZ_LD * D_MODEL, D_MODEL,
          nullptr, xz, XZ_LD, 0, nullptr, 0, R, XZ_LD, D_MODEL, 0);

      conv_silu<<<dim3(D_INNER / 256, L_SEQ, bc), 256, 0, stream>>>(
          xz, cw + (size_t)l * D_INNER * D_CONV, cb + (size_t)l * D_INNER,
          xc, xcb);

      // x_proj partials: 4-way K-split over K=2048 (hs window is dead here)
      gemm_mfma<<<dim3(R / 128, 1, 4), 256, 0, stream>>>(
          xcb, D_INNER, xpw_b + (size_t)l * PROJ_N * D_INNER, D_INNER,
          nullptr, ppart, PROJ_N, (size_t)R * PROJ_N, nullptr, 0,
          R, PROJ_N, 512, 0);
      xproj_combine<<<(R * PROJ_N / 4 + 255) / 256, 256, 0, stream>>>(
          ppart, proj, projb, R * PROJ_N / 4, (size_t)R * PROJ_N / 4);

      // dt = softplus(proj[:,:64] @ dtw[l]^T + dtb[l]) -> xm half of xz
      gemm_mfma<<<dim3(R / 128, D_INNER / 128), 256, 0, stream>>>(
          projb, PROJ_N, dtw_b + (size_t)l * D_INNER * DT_RANK, DT_RANK,
          dtb + (size_t)l * D_INNER, xz, XZ_LD, 0, nullptr, 0,
          R, D_INNER, 64, 1);

      // selective scan + D-skip + silu(z); writes y bf16 into xcb
      scan4<<<dim3(D_INNER / 64, bc), 256, 0, stream>>>(
          xz, xc, proj, Alog + (size_t)l * D_INNER * D_STATE,
          Dp + (size_t)l * D_INNER, xcb);

      // hs = y @ opw[l]^T      (R x 1024, K=2048)
      gemm_mfma<<<dim3(R / 128, D_MODEL / 128), 256, 0, stream>>>(
          xcb, D_INNER, opw_b + (size_t)l * D_MODEL * D_INNER, D_INNER,
          nullptr, hs, D_MODEL, 0, nullptr, 0, R, D_MODEL, D_INNER, 0);
    }

    pool_norm<<<bc * TT, 256, 0, stream>>>(hs, res, normfw, out, b0);
  }
}

// Round 6
// 8443.082 us; speedup vs baseline: 4.6531x; 1.1804x over previous
//
#include <hip/hip_runtime.h>
#include <hip/hip_bf16.h>
#include <math.h>

#define D_MODEL 1024
#define D_INNER 2048
#define D_STATE 16
#define D_CONV 4
#define DT_RANK 64
#define N_LAYER 8
#define INPUT_DIM 256
#define BATCH 16
#define TT 64
#define S_IN 13
#define SEQ_S 16                 // S_IN + 3
#define L_SEQ 1024               // TT * SEQ_S
#define XZ_LD (2 * D_INNER)      // 4096
#define PROJ_N 96                // DT_RANK + 2*D_STATE
#define EPS 1e-5f

typedef __attribute__((ext_vector_type(8))) short short8;   // 8 x bf16 (4 VGPRs)
typedef __attribute__((ext_vector_type(4))) float f32x4;    // MFMA acc

// fp32 -> bf16 bits, round-to-nearest-even
__device__ __forceinline__ unsigned short f2bu(float x) {
  unsigned int u = __float_as_uint(x);
  unsigned int r = (u + 0x7fffu + ((u >> 16) & 1u)) >> 16;
  return (unsigned short)r;
}
// bf16 bits -> fp32
__device__ __forceinline__ float bu2f(unsigned short u) {
  return __uint_as_float((unsigned int)u << 16);
}

__device__ __forceinline__ void gload_lds16(const void* g, void* l) {
  __builtin_amdgcn_global_load_lds(
      (const __attribute__((address_space(1))) void*)g,
      (__attribute__((address_space(3))) void*)l, 16, 0, 0);
}

// ---------------------------------------------------------------------------
// bf16 MFMA GEMM: D[M,N] = A[M,K](bf16) @ W[N,K](bf16)^T (+bias)(+act)
// 128x128 tile, BK=32, 4 waves x (4x4 of 16x16x32 MFMA), global_load_lds.
// K-split via gridDim.z (slice z -> C + z*cPartStride).
// Outputs optional: C fp32 (accum: C += v), Cb bf16.
// ---------------------------------------------------------------------------
__global__ __launch_bounds__(256) void gemm_mfma(
    const unsigned short* __restrict__ A, int lda,
    const unsigned short* __restrict__ W, int ldw,
    const float* __restrict__ bias,
    float* __restrict__ C, int ldc, size_t cPartStride, int accum,
    unsigned short* __restrict__ Cb, int ldcb,
    int M, int N, int kLen, int act)
{
  __shared__ unsigned short As[128 * 32];  // 8 KB
  __shared__ unsigned short Ws[128 * 32];  // 8 KB
  const int tid  = threadIdx.x;
  const int wave = tid >> 6;
  const int lane = tid & 63;
  const int m0 = blockIdx.x * 128;
  const int n0 = blockIdx.y * 128;
  const int wm = (wave & 1) * 64;
  const int wn = (wave >> 1) * 64;
  const int kStart = blockIdx.z * kLen;
  if (C) C += (size_t)blockIdx.z * cPartStride;

  const int srow = (lane >> 2);
  const int scol = (lane & 3) * 8;         // bf16 elements

  f32x4 acc[4][4] = {};

  for (int k0 = kStart; k0 < kStart + kLen; k0 += 32) {
#pragma unroll
    for (int i = 0; i < 2; ++i) {
      int rowA = m0 + wave * 32 + i * 16 + srow;
      if (rowA > M - 1) rowA = M - 1;
      gload_lds16(A + (size_t)rowA * lda + k0 + scol,
                  &As[(wave * 32 + i * 16) * 32]);
      int rowW = n0 + wave * 32 + i * 16 + srow;
      if (rowW > N - 1) rowW = N - 1;
      gload_lds16(W + (size_t)rowW * ldw + k0 + scol,
                  &Ws[(wave * 32 + i * 16) * 32]);
    }
    __syncthreads();

    short8 af[4], bf[4];
#pragma unroll
    for (int mi = 0; mi < 4; ++mi)
      af[mi] = *(const short8*)&As[(wm + mi * 16 + (lane & 15)) * 32 + (lane >> 4) * 8];
#pragma unroll
    for (int ni = 0; ni < 4; ++ni)
      bf[ni] = *(const short8*)&Ws[(wn + ni * 16 + (lane & 15)) * 32 + (lane >> 4) * 8];
#pragma unroll
    for (int mi = 0; mi < 4; ++mi)
#pragma unroll
      for (int ni = 0; ni < 4; ++ni)
        acc[mi][ni] = __builtin_amdgcn_mfma_f32_16x16x32_bf16(
            af[mi], bf[ni], acc[mi][ni], 0, 0, 0);
    __syncthreads();
  }

  // epilogue: C/D layout col=lane&15, row=(lane>>4)*4+r   [m89-verified]
#pragma unroll
  for (int mi = 0; mi < 4; ++mi) {
#pragma unroll
    for (int ni = 0; ni < 4; ++ni) {
      const int col = n0 + wn + ni * 16 + (lane & 15);
      if (col >= N) continue;
#pragma unroll
      for (int r = 0; r < 4; ++r) {
        const int row = m0 + wm + mi * 16 + (lane >> 4) * 4 + r;
        if (row >= M) continue;
        float v = acc[mi][ni][r];
        if (bias) v += bias[col];
        if (act == 1) v = (v > 20.f) ? v : log1pf(__expf(v));  // softplus
        if (C) {
          float o = v;
          if (accum) o += C[(size_t)row * ldc + col];
          C[(size_t)row * ldc + col] = o;
        }
        if (Cb) Cb[(size_t)row * ldcb + col] = f2bu(v);
      }
    }
  }
}

// ---------------------------------------------------------------------------
// Sum 4 K-split partials of x_proj -> proj fp32 + projb bf16
// ---------------------------------------------------------------------------
__global__ __launch_bounds__(256) void xproj_combine(
    const float* __restrict__ part, float* __restrict__ proj,
    unsigned short* __restrict__ projb, int n4, size_t stride4)
{
  int i = blockIdx.x * 256 + threadIdx.x;
  if (i >= n4) return;
  float4 a = ((const float4*)part)[i];
  float4 b = ((const float4*)part)[i + stride4];
  float4 c = ((const float4*)part)[i + 2 * stride4];
  float4 d = ((const float4*)part)[i + 3 * stride4];
  float4 v = make_float4(a.x + b.x + c.x + d.x, a.y + b.y + c.y + d.y,
                         a.z + b.z + c.z + d.z, a.w + b.w + c.w + d.w);
  ((float4*)proj)[i] = v;
  ushort4 o;
  o.x = f2bu(v.x); o.y = f2bu(v.y); o.z = f2bu(v.z); o.w = f2bu(v.w);
  ((ushort4*)projb)[i] = o;
}

// ---------------------------------------------------------------------------
// generic fp32 -> bf16 conversion (float4 vectorized)
// ---------------------------------------------------------------------------
__global__ __launch_bounds__(256) void cvt_bf16(
    const float* __restrict__ in, unsigned short* __restrict__ out, int n4)
{
  int i = blockIdx.x * 256 + threadIdx.x;
  if (i < n4) {
    float4 v = ((const float4*)in)[i];
    ushort4 o;
    o.x = f2bu(v.x); o.y = f2bu(v.y); o.z = f2bu(v.z); o.w = f2bu(v.w);
    ((ushort4*)out)[i] = o;
  }
}

// ---------------------------------------------------------------------------
__device__ __forceinline__ float block_reduce_sum_256(float v)
{
  __shared__ float red[4];
#pragma unroll
  for (int off = 32; off > 0; off >>= 1) v += __shfl_xor(v, off, 64);
  const int tid = threadIdx.x;
  if ((tid & 63) == 0) red[tid >> 6] = v;
  __syncthreads();
  return red[0] + red[1] + red[2] + red[3];
}

// ---------------------------------------------------------------------------
// Token assembly: res = concat([cls, h, 0, 0]) + pe   (res carry = hs+res)
// ---------------------------------------------------------------------------
__global__ __launch_bounds__(256) void seq_build(
    const float* __restrict__ hflat, const float* __restrict__ cls,
    float* __restrict__ res)
{
  const int row = blockIdx.x;            // b_local*1024 + l
  const int bl = row >> 10;
  const int l = row & (L_SEQ - 1);
  const int t = l >> 4;
  const int s = l & 15;
  const int tid = threadIdx.x;

  float4 v;
  if (s == 0) {
    v = ((const float4*)cls)[tid];
  } else if (s <= S_IN) {
    const size_t hrow = ((size_t)(bl * TT + t) * S_IN + (s - 1)) * D_MODEL;
    v = ((const float4*)(hflat + hrow))[tid];
  } else {
    v = make_float4(0.f, 0.f, 0.f, 0.f);
  }

  const float cexp = -logf(10000.f) / (float)D_MODEL;
  float pe[4];
#pragma unroll
  for (int j = 0; j < 4; ++j) {
    int d = tid * 4 + j;
    int i2 = d & ~1;
    float ang = (float)t * expf((float)i2 * cexp);
    pe[j] = (d & 1) ? cosf(ang) : sinf(ang);
  }
  v.x += pe[0]; v.y += pe[1]; v.z += pe[2]; v.w += pe[3];

  ((float4*)(res + (size_t)row * D_MODEL))[tid] = v;
}

// ---------------------------------------------------------------------------
// hn(bf16) = rmsnorm(res) * w   (read-only on res; out_proj accumulates res)
// ---------------------------------------------------------------------------
__global__ __launch_bounds__(256) void rmsnorm_only(
    const float* __restrict__ res, unsigned short* __restrict__ hnb,
    const float* __restrict__ w)
{
  const int row = blockIdx.x;
  const int tid = threadIdx.x;
  const size_t base = (size_t)row * D_MODEL;
  float4 r = ((const float4*)(res + base))[tid];
  float ss = r.x * r.x + r.y * r.y + r.z * r.z + r.w * r.w;
  ss = block_reduce_sum_256(ss);
  const float scale = rsqrtf(ss * (1.f / (float)D_MODEL) + EPS);
  float4 wv = ((const float4*)w)[tid];
  ushort4 o;
  o.x = f2bu(r.x * scale * wv.x);
  o.y = f2bu(r.y * scale * wv.y);
  o.z = f2bu(r.z * scale * wv.z);
  o.w = f2bu(r.w * scale * wv.w);
  ((ushort4*)(hnb + base))[tid] = o;
}

// ---------------------------------------------------------------------------
// Depthwise causal conv (K=4) + silu on bf16 xm; writes u bf16 (xcb)
// ---------------------------------------------------------------------------
__global__ __launch_bounds__(256) void conv_silu(
    const unsigned short* __restrict__ xzb, const float* __restrict__ cw,
    const float* __restrict__ cb, unsigned short* __restrict__ xcb)
{
  const int c = blockIdx.x * 256 + threadIdx.x;
  const int t = blockIdx.y;
  const int bl = blockIdx.z;
  const size_t row = (size_t)bl * L_SEQ + t;

  const float w0 = cw[c * D_CONV + 0];
  const float w1 = cw[c * D_CONV + 1];
  const float w2 = cw[c * D_CONV + 2];
  const float w3 = cw[c * D_CONV + 3];

  float acc = cb[c];
  if (t >= 3) acc = fmaf(w0, bu2f(xzb[(row - 3) * XZ_LD + c]), acc);
  if (t >= 2) acc = fmaf(w1, bu2f(xzb[(row - 2) * XZ_LD + c]), acc);
  if (t >= 1) acc = fmaf(w2, bu2f(xzb[(row - 1) * XZ_LD + c]), acc);
  acc = fmaf(w3, bu2f(xzb[row * XZ_LD + c]), acc);

  acc = acc / (1.f + __expf(-acc));      // silu
  xcb[row * D_INNER + c] = f2bu(acc);
}

// ---------------------------------------------------------------------------
// scan5: 4 states/lane, 4 lanes/channel; bf16 dt/z/u; register pipeline
// (4 rotating sets, prefetch distance 3). y bf16 overwrites u in place
// (element (t,ch) written at step t; u[t'] prefetched at t'-3 < write t'
// only for t' > t — disjoint elements, wave-synchronous => safe).
// Grid: (D_INNER/64, bc) x 256 thr. bc=16 => 512 blocks = 8 waves/CU.
// ---------------------------------------------------------------------------
__global__ __launch_bounds__(256) void scan5(
    const unsigned short* __restrict__ xzb, unsigned short* xcb,
    const float* __restrict__ proj,
    const float* __restrict__ Alog, const float* __restrict__ Dp)
{
  const int tid  = threadIdx.x;
  const int lane = tid & 63;
  const int wave = tid >> 6;
  const int chl  = lane >> 2;            // channel within wave (0..15)
  const int sq   = lane & 3;             // state quad
  const int ch   = blockIdx.x * 64 + wave * 16 + chl;
  const int s0   = sq * 4;
  const int bl   = blockIdx.y;
  const size_t base = (size_t)bl * L_SEQ;

  float A[4], h[4] = {0.f, 0.f, 0.f, 0.f};
#pragma unroll
  for (int k = 0; k < 4; ++k)
    A[k] = -__expf(Alog[(size_t)ch * D_STATE + s0 + k]);
  const float Dv = Dp[ch];

  float pdt[4], pz[4], pu[4];
  float4 pB[4], pC[4];

#define SCAN_LOAD(slot, t)                                                    \
  {                                                                           \
    const size_t r_ = base + (size_t)(t);                                     \
    pdt[slot] = bu2f(xzb[r_ * XZ_LD + ch]);                                   \
    pz[slot]  = bu2f(xzb[r_ * XZ_LD + D_INNER + ch]);                         \
    pu[slot]  = bu2f(xcb[r_ * D_INNER + ch]);                                 \
    pB[slot]  = *(const float4*)&proj[r_ * PROJ_N + DT_RANK + s0];            \
    pC[slot]  = *(const float4*)&proj[r_ * PROJ_N + DT_RANK + D_STATE + s0];  \
  }

  SCAN_LOAD(0, 0)
  SCAN_LOAD(1, 1)
  SCAN_LOAD(2, 2)

#pragma unroll 4
  for (int t = 0; t < L_SEQ; ++t) {
    const int sl = t & 3;
    int tn = t + 3;
    if (tn > L_SEQ - 1) tn = L_SEQ - 1;   // tail: harmless re-read
    SCAN_LOAD((t + 3) & 3, tn)

    const float dtv = pdt[sl];
    const float u   = pu[sl];
    const float du  = dtv * u;
    const float4 B4 = pB[sl];
    const float4 C4 = pC[sl];
    const float Bk[4] = {B4.x, B4.y, B4.z, B4.w};
    const float Ck[4] = {C4.x, C4.y, C4.z, C4.w};
    float yv = 0.f;
#pragma unroll
    for (int k = 0; k < 4; ++k) {
      const float dA = __expf(dtv * A[k]);
      h[k] = fmaf(dA, h[k], du * Bk[k]);
      yv = fmaf(h[k], Ck[k], yv);
    }
    yv += __shfl_xor(yv, 1, 64);
    yv += __shfl_xor(yv, 2, 64);
    if (sq == 0) {
      const float zv = pz[sl];
      const float g = zv / (1.f + __expf(-zv));     // silu(z)
      xcb[(base + t) * D_INNER + ch] = f2bu(fmaf(Dv, u, yv) * g);
    }
  }
#undef SCAN_LOAD
}

// ---------------------------------------------------------------------------
// Final pooled rmsnorm on cls rows (res already holds hs+res)
// ---------------------------------------------------------------------------
__global__ __launch_bounds__(256) void pool_norm(
    const float* __restrict__ res, const float* __restrict__ w,
    float* __restrict__ out, int b0)
{
  const int idx = blockIdx.x;                      // b_local*64 + t
  const int bl = idx >> 6;
  const int t = idx & 63;
  const size_t base = ((size_t)bl * L_SEQ + (size_t)t * SEQ_S) * D_MODEL;
  const int tid = threadIdx.x;
  float4 v = ((const float4*)(res + base))[tid];
  float ss = v.x * v.x + v.y * v.y + v.z * v.z + v.w * v.w;
  ss = block_reduce_sum_256(ss);
  const float scale = rsqrtf(ss * (1.f / (float)D_MODEL) + EPS);
  float4 wv = ((const float4*)w)[tid];
  float4 o = make_float4(v.x * scale * wv.x, v.y * scale * wv.y,
                         v.z * scale * wv.z, v.w * scale * wv.w);
  const size_t orow = (size_t)((b0 + bl) * TT + t) * D_MODEL;
  ((float4*)(out + orow))[tid] = o;
}

// ---------------------------------------------------------------------------
extern "C" void kernel_launch(void* const* d_in, const int* in_sizes, int n_in,
                              void* d_out, int out_size, void* d_ws, size_t ws_size,
                              hipStream_t stream)
{
  const float* x      = (const float*)d_in[0];
  // d_in[1] = tt (int scalar, == 64): compiled in as TT
  const float* w_in   = (const float*)d_in[2];
  const float* b_in   = (const float*)d_in[3];
  const float* cls    = (const float*)d_in[4];
  const float* norm_w = (const float*)d_in[5];
  const float* ipw    = (const float*)d_in[6];
  const float* cw     = (const float*)d_in[7];
  const float* cb     = (const float*)d_in[8];
  const float* xpw    = (const float*)d_in[9];
  const float* dtw    = (const float*)d_in[10];
  const float* dtb    = (const float*)d_in[11];
  const float* Alog   = (const float*)d_in[12];
  const float* Dp     = (const float*)d_in[13];
  const float* opw    = (const float*)d_in[14];
  const float* normfw = (const float*)d_in[15];
  float* out = (float*)d_out;

  // ---- bf16 weight/x region (elements) ----
  const size_t N_WIN = (size_t)D_MODEL * INPUT_DIM;
  const size_t N_IPW = (size_t)N_LAYER * XZ_LD * D_MODEL;
  const size_t N_XPW = (size_t)N_LAYER * PROJ_N * D_INNER;
  const size_t N_DTW = (size_t)N_LAYER * D_INNER * DT_RANK;
  const size_t N_OPW = (size_t)N_LAYER * D_MODEL * D_INNER;
  const size_t N_XB  = (size_t)BATCH * TT * S_IN * INPUT_DIM;
  const size_t N_BF  = N_WIN + N_IPW + N_XPW + N_DTW + N_OPW + N_XB;

  // per-batch activation bytes:
  // res f32 4096 + xzb bf16 8192 + xcb bf16 4096 + proj f32 384
  // + projb bf16 192 + hnb bf16 2048  = 19008 B/row
  const size_t perB = (size_t)L_SEQ * 19008;
  int bc = 0;
  for (int c = 16; c >= 1; c >>= 1)
    if (N_BF * 2 + perB * (size_t)c <= ws_size) { bc = c; break; }
  if (bc == 0) return;

  const int R = bc * L_SEQ;

  unsigned short* w_in_b = (unsigned short*)d_ws;
  unsigned short* ipw_b  = w_in_b + N_WIN;
  unsigned short* xpw_b  = ipw_b + N_IPW;
  unsigned short* dtw_b  = xpw_b + N_XPW;
  unsigned short* opw_b  = dtw_b + N_DTW;
  unsigned short* x_b    = opw_b + N_OPW;
  float*          res  = (float*)(x_b + N_XB);
  unsigned short* xzb  = (unsigned short*)(res + (size_t)R * D_MODEL);
  unsigned short* xcb  = xzb + (size_t)R * XZ_LD;
  float*          proj = (float*)(xcb + (size_t)R * D_INNER);
  unsigned short* projb = (unsigned short*)(proj + (size_t)R * PROJ_N);
  unsigned short* hnb   = projb + (size_t)R * PROJ_N;
  // x_proj K-split partials overlay hnb (dead between in_proj and next
  // rmsnorm): R*384*4 B <= R*2048 B. hflat (input GEMM out) overlays xzb.
  float* ppart = (float*)hnb;
  float* hflat = (float*)xzb;

  // ---- weight + x conversion (once per launch; ws re-poisoned each call) ----
  cvt_bf16<<<(int)((N_WIN/4 + 255)/256), 256, 0, stream>>>(w_in, w_in_b, (int)(N_WIN/4));
  cvt_bf16<<<(int)((N_IPW/4 + 255)/256), 256, 0, stream>>>(ipw, ipw_b, (int)(N_IPW/4));
  cvt_bf16<<<(int)((N_XPW/4 + 255)/256), 256, 0, stream>>>(xpw, xpw_b, (int)(N_XPW/4));
  cvt_bf16<<<(int)((N_DTW/4 + 255)/256), 256, 0, stream>>>(dtw, dtw_b, (int)(N_DTW/4));
  cvt_bf16<<<(int)((N_OPW/4 + 255)/256), 256, 0, stream>>>(opw, opw_b, (int)(N_OPW/4));
  cvt_bf16<<<(int)((N_XB/4  + 255)/256), 256, 0, stream>>>(x,   x_b,   (int)(N_XB/4));

  for (int b0 = 0; b0 < BATCH; b0 += bc) {
    // 1. input projection: hflat = x_chunk @ w_in^T + b_in (fp32, in xzb)
    const int Mx = bc * TT * S_IN;
    gemm_mfma<<<dim3((Mx + 127) / 128, D_MODEL / 128), 256, 0, stream>>>(
        x_b + (size_t)b0 * TT * S_IN * INPUT_DIM, INPUT_DIM,
        w_in_b, INPUT_DIM, b_in, hflat, D_MODEL, 0, 0, nullptr, 0,
        Mx, D_MODEL, INPUT_DIM, 0);

    // 2. token assembly + positional encoding: res = seq
    seq_build<<<R, 256, 0, stream>>>(hflat, cls, res);

    for (int l = 0; l < N_LAYER; ++l) {
      rmsnorm_only<<<R, 256, 0, stream>>>(res, hnb,
          norm_w + (size_t)l * D_MODEL);

      // xzb = bf16(hn @ ipw[l]^T)   (R x 4096, K=1024)
      gemm_mfma<<<dim3(R / 128, XZ_LD / 128), 256, 0, stream>>>(
          hnb, D_MODEL, ipw_b + (size_t)l * XZ_LD * D_MODEL, D_MODEL,
          nullptr, nullptr, 0, 0, 0, xzb, XZ_LD, R, XZ_LD, D_MODEL, 0);

      conv_silu<<<dim3(D_INNER / 256, L_SEQ, bc), 256, 0, stream>>>(
          xzb, cw + (size_t)l * D_INNER * D_CONV, cb + (size_t)l * D_INNER,
          xcb);

      // x_proj partials: 4-way K-split over K=2048 (hnb window is dead)
      gemm_mfma<<<dim3(R / 128, 1, 4), 256, 0, stream>>>(
          xcb, D_INNER, xpw_b + (size_t)l * PROJ_N * D_INNER, D_INNER,
          nullptr, ppart, PROJ_N, (size_t)R * PROJ_N, 0, nullptr, 0,
          R, PROJ_N, 512, 0);
      xproj_combine<<<(R * PROJ_N / 4 + 255) / 256, 256, 0, stream>>>(
          ppart, proj, projb, R * PROJ_N / 4, (size_t)R * PROJ_N / 4);

      // dt = bf16(softplus(proj[:,:64] @ dtw[l]^T + dtb[l])) -> xm half of xzb
      gemm_mfma<<<dim3(R / 128, D_INNER / 128), 256, 0, stream>>>(
          projb, PROJ_N, dtw_b + (size_t)l * D_INNER * DT_RANK, DT_RANK,
          dtb + (size_t)l * D_INNER, nullptr, 0, 0, 0, xzb, XZ_LD,
          R, D_INNER, 64, 1);

      // selective scan + D-skip + silu(z); y bf16 overwrites u in xcb
      scan5<<<dim3(D_INNER / 64, bc), 256, 0, stream>>>(
          xzb, xcb, proj, Alog + (size_t)l * D_INNER * D_STATE,
          Dp + (size_t)l * D_INNER);

      // res += y @ opw[l]^T      (R x 1024, K=2048) — accumulate epilogue
      gemm_mfma<<<dim3(R / 128, D_MODEL / 128), 256, 0, stream>>>(
          xcb, D_INNER, opw_b + (size_t)l * D_MODEL * D_INNER, D_INNER,
          nullptr, res, D_MODEL, 0, 1, nullptr, 0, R, D_MODEL, D_INNER, 0);
    }

    pool_norm<<<bc * TT, 256, 0, stream>>>(res, normfw, out, b0);
  }
}